// Round 11
// baseline (11516.920 us; speedup 1.0000x reference)
//
#include <hip/hip_runtime.h>
#include <stdint.h>

// ---------------------------------------------------------------------------
// AWD-LSTM eval forward.  T=256, B=256, H=1024, FEAT=319 (=300+7+12), C=13.
// Layer1's recurrent carry is ignored by the reference -> only layer0 is
// sequential; layer1+decoder are parallel over rows.
// Round 11: persistent layer0 with FULLY DISTRIBUTED flag barrier.
// Failure catalog: R4 fence L2-flush; R7/R8 serialized atomic-RMW cascade
// (~15us); R10 central super-flag line hammered by 511 pollers (~29us).
// Work itself is ~4.4us/step (R9).  This round: per-step sync is per-Mb-group
// (4 independent 128-block pipelines; consumer (Mb,Nb) reads only h rows
// [Mb,Mb+64)); each block checks its group's 128 flags DIRECTLY -- one
// agent-scope atomic load per thread (128 addrs = 16 lines, no hot line) +
// __syncthreads_and.  No RMW, no relay.  K-loop/epilogue/publish = R10
// verbatim (fresh-slot h + agent atomic u32 pairs, c-state in registers).
// ---------------------------------------------------------------------------

typedef __attribute__((ext_vector_type(8))) short bf16x8;
typedef __attribute__((ext_vector_type(4))) float f32x4;

#define SLOT 262144ull  // 256*1024 elements per (B,H) slab

__device__ __forceinline__ uint16_t f2bf(float f) {
  uint32_t u = __float_as_uint(f);
  u += 0x7fffu + ((u >> 16) & 1u);
  return (uint16_t)(u >> 16);
}
__device__ __forceinline__ float bf2f(uint16_t h) {
  return __uint_as_float(((uint32_t)h) << 16);
}
__device__ __forceinline__ float sigmoidf_(float x) {
  return __builtin_amdgcn_rcpf(1.0f + __expf(-x));
}
__device__ __forceinline__ float tanhf_(float x) {
  return 1.0f - 2.0f * __builtin_amdgcn_rcpf(__expf(2.0f * x) + 1.0f);
}
__device__ __forceinline__ void gload_lds16(const void* g, void* l) {
  __builtin_amdgcn_global_load_lds(
      (const __attribute__((address_space(1))) void*)g,
      (__attribute__((address_space(3))) void*)l, 16, 0, 0);
}
// LDS tile: row-major [rows][32 k] bf16; four 16B chunks of each row stored
// permuted: chunk_pos = chunk ^ ((row>>1)&3)  -> ~2-way banks
__device__ __forceinline__ bf16x8 lds_frag(const uint16_t* base, int row, int kc) {
  const uint16_t* p = base + row * 32 + ((kc ^ ((row >> 1) & 3)) << 3);
  return *(const bf16x8*)p;
}
__device__ __forceinline__ f32x4 mfma16(bf16x8 a, bf16x8 b, f32x4 c) {
  return __builtin_amdgcn_mfma_f32_16x16x32_bf16(a, b, c, 0, 0, 0);
}

// ---------------- weight prep ----------------
__global__ __launch_bounds__(256) void k_prep_w0(
    const float* __restrict__ wi0, const float* __restrict__ bi0,
    const float* __restrict__ wh0, const float* __restrict__ bh0,
    uint16_t* __restrict__ W0c, float* __restrict__ b0) {
  int r = blockIdx.x;            // interleaved output row: unit j, gate p
  int p = r & 3, j = r >> 2;
  int src = p * 1024 + j;
  const float* wi = wi0 + (size_t)src * 319;
  const float* wh = wh0 + (size_t)src * 1024;
  uint16_t* dst = W0c + (size_t)r * 1344;
  for (int k = threadIdx.x; k < 1344; k += 256) {
    float v;
    if (k < 319) v = wi[k];
    else if (k == 319) v = 0.0f;
    else v = wh[k - 320];
    dst[k] = f2bf(v);
  }
  if (threadIdx.x == 0) b0[r] = bi0[src] + bh0[src];
}

__global__ __launch_bounds__(256) void k_prep_w1(
    const float* __restrict__ wi1, const float* __restrict__ bi1,
    const float* __restrict__ wh1, const float* __restrict__ bh1,
    uint16_t* __restrict__ W1c, float* __restrict__ b1) {
  int r = blockIdx.x;
  int p = r & 3, j = r >> 2;
  int src = p * 1024 + j;
  const float* wi = wi1 + (size_t)src * 1024;
  const float* wh = wh1 + (size_t)src * 1024;
  uint16_t* dst = W1c + (size_t)r * 2048;
  for (int k = threadIdx.x; k < 2048; k += 256) {
    float v = (k < 1024) ? wi[k] : wh[k - 1024];
    dst[k] = f2bf(v);
  }
  if (threadIdx.x == 0) b1[r] = bi1[src] + bh1[src];
}

__global__ __launch_bounds__(256) void k_init(
    const float* __restrict__ h_init, const float* __restrict__ c_init,
    uint16_t* __restrict__ h_slot, float* __restrict__ c_state,
    uint32_t* __restrict__ flags) {
  int i = blockIdx.x * 256 + threadIdx.x;  // 262144 = 256*1024
  h_slot[i] = f2bf(h_init[i]);             // layer0 slice of h_init
  c_state[i] = c_init[i];
  if (i < 131072) flags[i] = 0;            // 256 steps x 512 flags
}

// ---------------- embedding + concat -> x_bf ----------------
__global__ __launch_bounds__(256) void k_embed(
    const int* __restrict__ tokens, const float* __restrict__ casing,
    const float* __restrict__ pos, const float* __restrict__ emb,
    uint16_t* __restrict__ x_bf) {
  int row = blockIdx.x * 4 + (threadIdx.x >> 6);  // (t*256+b)
  int l = threadIdx.x & 63;
  int tok = tokens[row];
  const float* er = emb + (size_t)tok * 300;
  uint16_t* xr = x_bf + (size_t)row * 320;
#pragma unroll
  for (int c0 = 0; c0 < 320; c0 += 64) {
    int c = c0 + l;
    float v;
    if (c < 300) v = er[c];
    else if (c < 307) v = casing[(size_t)row * 7 + (c - 300)];
    else if (c < 319) v = pos[(size_t)row * 12 + (c - 307)];
    else v = 0.0f;
    xr[c] = f2bf(v);
  }
}

// ---------------- persistent layer0 chunk (CH steps, 1 launch) ----------------
// Grid 512 = 2 blocks/CU.  Block = (Mb 64-row batch tile, Nb 32-col tile),
// XCD-chunked swizzle.  Per step: R9's proven K-loop (4 waves 2x2 over
// (32M,16N), vmcnt(4) ring, one s_barrier/iter), fused cell epilogue (c in
// regs), fresh-slot h publish via agent atomic u32 pairs, then the
// distributed per-Mb-group flag barrier (group = lid&3, member = lid>>2).
__global__ __launch_bounds__(256, 2) void k_l0chunk(
    const uint16_t* __restrict__ x_bf, const uint16_t* __restrict__ W0c,
    const float* __restrict__ b0, uint16_t* __restrict__ h0buf,
    uint16_t* __restrict__ c0buf, float* __restrict__ c_st,
    uint32_t* __restrict__ flags, int t0, int CH, int in_s0) {
  __shared__ __align__(16) uint16_t As[4][2048];  // 64 rows x 32 k
  __shared__ __align__(16) uint16_t Bs[4][1024];  // 32 rows x 32 k
  __shared__ __align__(16) float epi[4][16][20];
  const int tid = threadIdx.x;
  const int w = tid >> 6, l = tid & 63;
  const int wr = w >> 1, wc = w & 1;
  const int lid = (blockIdx.x & 7) * 64 + (blockIdx.x >> 3);  // bijective
  const int Mb = (lid & 3) * 64;    // batch tile (64 rows)
  const int Nb = (lid >> 2) * 32;   // col tile (32 interleaved cols)

  const int sc = (l & 3) ^ ((l >> 3) & 3);
  const int arow = Mb + w * 16 + (l >> 2);  // A row this lane stages
  const uint16_t* wrow =
      W0c + (size_t)(Nb + (w & 1) * 16 + (l >> 2)) * 1344 + sc * 8;

  // 2 cells/thread, fixed across steps; c in registers
  const int jbase = (Nb + wc * 16) >> 2;
  const int rr = l >> 2, jj = l & 3;
  int gidx2[2];
  float creg[2];
#pragma unroll
  for (int m = 0; m < 2; ++m) {
    int bg = Mb + wr * 32 + m * 16 + rr;
    gidx2[m] = bg * 1024 + jbase + jj;
    creg[m] = c_st[gidx2[m]];
  }

  for (int tl = 0; tl < CH; ++tl) {
    const int t = t0 + tl;
    const int is = (tl > 0) ? (tl - 1) : in_s0;
    const uint16_t* xrow = x_bf + ((size_t)t * 256 + arow) * 320 + sc * 8;
    const uint16_t* hrow =
        h0buf + (size_t)is * SLOT + (size_t)arow * 1024 + sc * 8;
    auto stage = [&](int kt, int buf) {
      int kg = kt * 32;
      const uint16_t* sA = (kt < 10) ? (xrow + kg) : (hrow + (kg - 320));
      gload_lds16(sA, &As[buf][w * 512]);
      gload_lds16(wrow + kg, &Bs[buf][(w & 1) * 512]);
    };

    f32x4 acc[2] = {};
    stage(0, 0);
    stage(1, 1);
    stage(2, 2);
    for (int kt = 0; kt < 42; ++kt) {
      __builtin_amdgcn_sched_barrier(0);
      if (kt < 40) asm volatile("s_waitcnt vmcnt(4)" ::: "memory");
      else if (kt == 40) asm volatile("s_waitcnt vmcnt(2)" ::: "memory");
      else asm volatile("s_waitcnt vmcnt(0)" ::: "memory");
      __builtin_amdgcn_s_barrier();
      __builtin_amdgcn_sched_barrier(0);
      if (kt < 39) stage(kt + 3, (kt + 3) & 3);
      const uint16_t* Ab = As[kt & 3];
      const uint16_t* Bb = Bs[kt & 3];
      bf16x8 a0 = lds_frag(Ab, wr * 32 + (l & 15), l >> 4);
      bf16x8 a1 = lds_frag(Ab, wr * 32 + 16 + (l & 15), l >> 4);
      bf16x8 q0 = lds_frag(Bb, wc * 16 + (l & 15), l >> 4);
      acc[0] = mfma16(a0, q0, acc[0]);
      acc[1] = mfma16(a1, q0, acc[1]);
    }

    // fused LSTM cell epilogue; h -> fresh slot tl (agent atomic u32 pairs)
    uint32_t* hc = (uint32_t*)(h0buf + (size_t)tl * SLOT);
    uint32_t* cc = (uint32_t*)(c0buf + (size_t)tl * SLOT);
#pragma unroll
    for (int m = 0; m < 2; ++m) {
#pragma unroll
      for (int r = 0; r < 4; ++r)
        epi[w][(l >> 4) * 4 + r][l & 15] = acc[m][r];
      asm volatile("s_waitcnt lgkmcnt(0)" ::: "memory");
      {
        f32x4 q = *(const f32x4*)&epi[w][rr][jj * 4];
        f32x4 bv = *(const f32x4*)&b0[(jbase + jj) * 4];
        float vi = sigmoidf_(q[0] + bv[0]);
        float vf = sigmoidf_(q[1] + bv[1]);
        float vo = sigmoidf_(q[2] + bv[2]);
        float vg = tanhf_(q[3] + bv[3]);
        float cn = vf * creg[m] + vi * vg;
        creg[m] = cn;
        float hh = vo * tanhf_(cn);
        uint32_t hu = f2bf(hh), cu = f2bf(cn);
        uint32_t hp = hu | ((uint32_t)__shfl_xor((int)hu, 1) << 16);
        uint32_t cp = cu | ((uint32_t)__shfl_xor((int)cu, 1) << 16);
        if ((l & 1) == 0) {
          size_t pidx = (size_t)(gidx2[m] >> 1);
          __hip_atomic_store(hc + pidx, hp, __ATOMIC_RELAXED,
                             __HIP_MEMORY_SCOPE_AGENT);
          cc[pidx] = cp;
        }
      }
      asm volatile("s_waitcnt lgkmcnt(0)" ::: "memory");
    }

    // distributed inter-step barrier, per Mb-group (128 blocks):
    // arrive = 1 release flag-store; wait = each thread atomically loads one
    // of the group's 128 flags (16 lines, no hot line) + __syncthreads_and.
    if (tl + 1 < CH) {
      __syncthreads();  // per-wave vmcnt drained -> all h stores are in L3
      uint32_t* fb = flags + (size_t)t * 512 + (size_t)(lid & 3) * 128;
      if (tid == 0)
        __hip_atomic_store(&fb[lid >> 2], 1u, __ATOMIC_RELEASE,
                           __HIP_MEMORY_SCOPE_AGENT);
      int spins = 0;
      for (;;) {
        uint32_t v = __hip_atomic_load(&fb[tid & 127], __ATOMIC_RELAXED,
                                       __HIP_MEMORY_SCOPE_AGENT);
        if (__syncthreads_and((int)(v != 0))) break;
        if (++spins > 50000) break;  // bounded: bug -> wrong, not hung
        __builtin_amdgcn_s_sleep(1);
      }
      __builtin_amdgcn_sched_barrier(0);
    }
  }
#pragma unroll
  for (int m = 0; m < 2; ++m) c_st[gidx2[m]] = creg[m];
}

// ---------------- layer1 GEMM over one chunk ----------------
// rows = CH*256; A row (t,b) = [h0(t,b) | h0(t,255-b)]  (slot tl of h0buf).
// tile 128x128, 4 waves (2x2) x (4x4 frags), fused cell epilogue.
// 1-D grid 64*CH, XCD-chunked swizzle: XCD k owns N-panels [4k,4k+4).
__global__ __launch_bounds__(256) void k_l1gemm(
    const uint16_t* __restrict__ h0buf, const uint16_t* __restrict__ W1c,
    const float* __restrict__ b1, const uint16_t* __restrict__ c0buf,
    uint16_t* __restrict__ h1buf) {
  __shared__ __align__(16) uint16_t As[128 * 32];
  __shared__ __align__(16) uint16_t Bs[128 * 32];
  __shared__ __align__(16) float epi[4][16][68];
  int tid = threadIdx.x;
  int w = tid >> 6, l = tid & 63;
  int wr = w >> 1, wc = w & 1;
  uint32_t G = gridDim.x;          // 64*CH (divisible by 8)
  uint32_t cpx = G >> 3;
  uint32_t lid = (blockIdx.x & 7) * cpx + (blockIdx.x >> 3);  // bijective
  uint32_t yyTot = G >> 5;         // 2*CH row-tiles per N-panel
  uint32_t nb = lid / yyTot;       // N-panel 0..31
  uint32_t yy = lid - nb * yyTot;  // row tile 0..2CH-1
  int Nb = (int)nb * 128;
  int tl = (int)(yy >> 1);
  int bbase = (int)(yy & 1) * 128;
  const uint16_t* hrow = h0buf + (size_t)tl * SLOT;
  const uint16_t* c0s = c0buf + (size_t)tl * SLOT;
  uint16_t* h1s = h1buf + (size_t)tl * SLOT;
  f32x4 acc[4][4] = {};

  int sc = (l & 3) ^ ((l >> 3) & 3);
  int srow0 = (w * 2 + 0) * 16 + (l >> 2);
  int srow1 = (w * 2 + 1) * 16 + (l >> 2);
  const uint16_t* hA0n = hrow + (size_t)(bbase + srow0) * 1024;
  const uint16_t* hA0f = hrow + (size_t)(255 - (bbase + srow0)) * 1024;
  const uint16_t* hA1n = hrow + (size_t)(bbase + srow1) * 1024;
  const uint16_t* hA1f = hrow + (size_t)(255 - (bbase + srow1)) * 1024;
  const uint16_t* wB0 = W1c + (size_t)(Nb + srow0) * 2048;
  const uint16_t* wB1 = W1c + (size_t)(Nb + srow1) * 2048;
  uint16_t* AsW0 = As + (w * 2 + 0) * 512;
  uint16_t* AsW1 = As + (w * 2 + 1) * 512;
  uint16_t* BsW0 = Bs + (w * 2 + 0) * 512;
  uint16_t* BsW1 = Bs + (w * 2 + 1) * 512;

  for (int kt = 0; kt < 64; ++kt) {
    int kg = kt * 32 + sc * 8;
    const uint16_t* sA0 = (kg < 1024) ? (hA0n + kg) : (hA0f + (kg - 1024));
    const uint16_t* sA1 = (kg < 1024) ? (hA1n + kg) : (hA1f + (kg - 1024));
    gload_lds16(sA0, AsW0);
    gload_lds16(sA1, AsW1);
    gload_lds16(wB0 + kg, BsW0);
    gload_lds16(wB1 + kg, BsW1);
    __syncthreads();
    bf16x8 a[4], q[4];
#pragma unroll
    for (int m = 0; m < 4; ++m) a[m] = lds_frag(As, wr * 64 + m * 16 + (l & 15), l >> 4);
#pragma unroll
    for (int n = 0; n < 4; ++n) q[n] = lds_frag(Bs, wc * 64 + n * 16 + (l & 15), l >> 4);
#pragma unroll
    for (int m = 0; m < 4; ++m)
#pragma unroll
      for (int n = 0; n < 4; ++n) acc[m][n] = mfma16(a[m], q[n], acc[m][n]);
    __syncthreads();
  }

  int jbase = (Nb + wc * 64) >> 2;
#pragma unroll
  for (int m = 0; m < 4; ++m) {
#pragma unroll
    for (int n = 0; n < 4; ++n)
#pragma unroll
      for (int r = 0; r < 4; ++r)
        epi[w][(l >> 4) * 4 + r][n * 16 + (l & 15)] = acc[m][n][r];
    asm volatile("s_waitcnt lgkmcnt(0)" ::: "memory");
#pragma unroll
    for (int it = 0; it < 4; ++it) {
      int pp = it * 64 + l;
      int rr = pp >> 4, j = pp & 15;
      f32x4 q = *(const f32x4*)&epi[w][rr][j * 4];
      f32x4 bv = *(const f32x4*)&b1[(size_t)(jbase + j) * 4];
      float vi = sigmoidf_(q[0] + bv[0]);
      float vf = sigmoidf_(q[1] + bv[1]);
      float vo = sigmoidf_(q[2] + bv[2]);
      float vg = tanhf_(q[3] + bv[3]);
      int rowl = wr * 64 + m * 16 + rr;
      int b = bbase + rowl;
      int jg = jbase + j;
      float c0v = bf2f(c0s[(size_t)(255 - b) * 1024 + jg]);
      float cn = vf * c0v + vi * vg;
      float hh = vo * tanhf_(cn);
      h1s[(size_t)b * 1024 + jg] = f2bf(hh);
    }
    asm volatile("s_waitcnt lgkmcnt(0)" ::: "memory");
  }
}

// ---------------- decoder over one chunk ----------------
__global__ __launch_bounds__(256) void k_decode(
    const uint16_t* __restrict__ h0buf, const uint16_t* __restrict__ h1buf,
    const float* __restrict__ dec_w, const float* __restrict__ dec_b,
    float* __restrict__ out, int t0) {
  int rowl = blockIdx.x * 4 + (threadIdx.x >> 6);  // chunk-local row
  int l = threadIdx.x & 63;
  int tl = rowl >> 8, b = rowl & 255;
  const uint16_t* h0 = h0buf + (size_t)tl * SLOT + (size_t)b * 1024;
  const uint16_t* h1 = h1buf + (size_t)tl * SLOT + (size_t)b * 1024;
  float acc[13];
#pragma unroll
  for (int c = 0; c < 13; ++c) acc[c] = 0.0f;
#pragma unroll
  for (int part = 0; part < 2; ++part) {
    const uint16_t* h = part ? h1 : h0;
    const float* wb = dec_w + part * 1024 + (size_t)l * 16;
    float hv[16];
    const bf16x8* hp = (const bf16x8*)(h + l * 16);
    bf16x8 v0 = hp[0];
    bf16x8 v1 = hp[1];
#pragma unroll
    for (int jj = 0; jj < 8; ++jj) {
      hv[jj] = bf2f((uint16_t)v0[jj]);
      hv[8 + jj] = bf2f((uint16_t)v1[jj]);
    }
#pragma unroll
    for (int c = 0; c < 13; ++c) {
      const float* wc = wb + (size_t)c * 2048;
      float s = 0.0f;
#pragma unroll
      for (int jj = 0; jj < 16; ++jj) s += hv[jj] * wc[jj];
      acc[c] += s;
    }
  }
#pragma unroll
  for (int c = 0; c < 13; ++c) {
    float v = acc[c];
#pragma unroll
    for (int off = 32; off > 0; off >>= 1) v += __shfl_xor(v, off, 64);
    acc[c] = v;
  }
  if (l == 0) {
    int t = t0 + tl;
    float* orow = out + ((size_t)t * 256 + b) * 13;
#pragma unroll
    for (int c = 0; c < 13; ++c) orow[c] = acc[c] + dec_b[c];
  }
}

// ---------------- host ----------------
extern "C" void kernel_launch(void* const* d_in, const int* in_sizes, int n_in,
                              void* d_out, int out_size, void* d_ws, size_t ws_size,
                              hipStream_t stream) {
  const int* tokens = (const int*)d_in[0];
  const float* casing = (const float*)d_in[1];
  const float* pos = (const float*)d_in[2];
  const float* emb = (const float*)d_in[3];
  const float* wi0 = (const float*)d_in[4];
  const float* bi0 = (const float*)d_in[5];
  const float* wh0 = (const float*)d_in[6];
  const float* bh0 = (const float*)d_in[7];
  const float* wi1 = (const float*)d_in[8];
  const float* bi1 = (const float*)d_in[9];
  const float* wh1 = (const float*)d_in[10];
  const float* bh1 = (const float*)d_in[11];
  const float* dec_w = (const float*)d_in[12];
  const float* dec_b = (const float*)d_in[13];
  const float* h_init = (const float*)d_in[14];
  const float* c_init = (const float*)d_in[15];
  float* out = (float*)d_out;
  (void)in_sizes; (void)n_in; (void)out_size;

  char* ws = (char*)d_ws;
  size_t off = 0;
  auto alloc = [&](size_t bytes) {
    char* p = ws + off;
    off += (bytes + 255) & ~(size_t)255;
    return p;
  };
  // fixed buffers (~70 MB)
  uint16_t* W0c = (uint16_t*)alloc(4096ull * 1344 * 2);
  float* b0 = (float*)alloc(4096 * 4);
  uint16_t* W1c = (uint16_t*)alloc(4096ull * 2048 * 2);
  float* b1 = (float*)alloc(4096 * 4);
  uint16_t* x_bf = (uint16_t*)alloc(65536ull * 320 * 2);
  float* c_st = (float*)alloc(SLOT * 4);
  uint32_t* flags = (uint32_t*)alloc(131072 * 4);  // 256 steps x 512

  // chunk size: (CH+1) + CH + CH slots of SLOT*2 bytes
  const size_t SB = SLOT * 2;  // 524288, 256-aligned
  int CH = 0;
  for (int c = 64; c >= 2; c >>= 1) {
    if (off + (size_t)(3 * c + 1) * SB + 4096 <= ws_size) { CH = c; break; }
  }
  if (CH == 0) return;  // ws too small (diagnostic: poisoned output)
  uint16_t* h0buf = (uint16_t*)alloc((size_t)(CH + 1) * SB);  // slot CH = h_init
  uint16_t* c0buf = (uint16_t*)alloc((size_t)CH * SB);
  uint16_t* h1buf = (uint16_t*)alloc((size_t)CH * SB);

  k_prep_w0<<<4096, 256, 0, stream>>>(wi0, bi0, wh0, bh0, W0c, b0);
  k_prep_w1<<<4096, 256, 0, stream>>>(wi1, bi1, wh1, bh1, W1c, b1);
  k_embed<<<16384, 256, 0, stream>>>(tokens, casing, pos, emb, x_bf);
  k_init<<<1024, 256, 0, stream>>>(h_init, c_init, h0buf + (size_t)CH * SLOT,
                                   c_st, flags);

  for (int t0 = 0; t0 < 256; t0 += CH) {
    // input slot for tl==0: h_init slot (CH) at t0==0, else prev chunk's
    // last slot (CH-1); within a launch slot CH-1 is read at tl==0 and only
    // rewritten at tl==CH-1 (flag barriers order it).
    int in_s0 = (t0 == 0) ? CH : CH - 1;
    k_l0chunk<<<512, 256, 0, stream>>>(x_bf, W0c, b0, h0buf, c0buf, c_st,
                                       flags, t0, CH, in_s0);
    k_l1gemm<<<64 * CH, 256, 0, stream>>>(h0buf, W1c, b1, c0buf, h1buf);
    k_decode<<<CH * 64, 256, 0, stream>>>(h0buf, h1buf, dec_w, dec_b, out, t0);
  }
}

// Round 12
// 10812.989 us; speedup vs baseline: 1.0651x; 1.0651x over previous
//
#include <hip/hip_runtime.h>
#include <stdint.h>

// ---------------------------------------------------------------------------
// AWD-LSTM eval forward.  T=256, B=256, H=1024, FEAT=319 (=300+7+12), C=13.
// Layer1's recurrent carry is ignored by the reference -> only layer0 is
// sequential; layer1+decoder are parallel over rows.
// Round 12: persistent layer0, SENSE-TREE barrier with private-line polling.
// Failure catalog: R4 fences (L2 flush); R7/R8 RMW arrive cascade (~15us);
// R10 one hot poll line (511 pollers); R11 poller explosion (my bug: 256
// pollers/block -> 131k loads/round).  Never tested until now: arrive =
// 1 release store/block (distinct lines); 1 reducer block per Mb-group scans
// its 128 arrive flags; fanout = 128 release stores to per-waiter PRIVATE
// 64B lines; waiter = ONE thread polling ITS OWN line, relaxed (fresh-slot
// publish makes acquire unnecessary -- 5 rounds correctness-proven).
// K-loop/epilogue/publish/slot logic identical to R10/R11 (both passed).
// ---------------------------------------------------------------------------

typedef __attribute__((ext_vector_type(8))) short bf16x8;
typedef __attribute__((ext_vector_type(4))) float f32x4;

#define SLOT 262144ull  // 256*1024 elements per (B,H) slab

__device__ __forceinline__ uint16_t f2bf(float f) {
  uint32_t u = __float_as_uint(f);
  u += 0x7fffu + ((u >> 16) & 1u);
  return (uint16_t)(u >> 16);
}
__device__ __forceinline__ float bf2f(uint16_t h) {
  return __uint_as_float(((uint32_t)h) << 16);
}
__device__ __forceinline__ float sigmoidf_(float x) {
  return __builtin_amdgcn_rcpf(1.0f + __expf(-x));
}
__device__ __forceinline__ float tanhf_(float x) {
  return 1.0f - 2.0f * __builtin_amdgcn_rcpf(__expf(2.0f * x) + 1.0f);
}
__device__ __forceinline__ void gload_lds16(const void* g, void* l) {
  __builtin_amdgcn_global_load_lds(
      (const __attribute__((address_space(1))) void*)g,
      (__attribute__((address_space(3))) void*)l, 16, 0, 0);
}
// LDS tile: row-major [rows][32 k] bf16; four 16B chunks of each row stored
// permuted: chunk_pos = chunk ^ ((row>>1)&3)  -> ~2-way banks
__device__ __forceinline__ bf16x8 lds_frag(const uint16_t* base, int row, int kc) {
  const uint16_t* p = base + row * 32 + ((kc ^ ((row >> 1) & 3)) << 3);
  return *(const bf16x8*)p;
}
__device__ __forceinline__ f32x4 mfma16(bf16x8 a, bf16x8 b, f32x4 c) {
  return __builtin_amdgcn_mfma_f32_16x16x32_bf16(a, b, c, 0, 0, 0);
}

// ---------------- weight prep ----------------
__global__ __launch_bounds__(256) void k_prep_w0(
    const float* __restrict__ wi0, const float* __restrict__ bi0,
    const float* __restrict__ wh0, const float* __restrict__ bh0,
    uint16_t* __restrict__ W0c, float* __restrict__ b0) {
  int r = blockIdx.x;            // interleaved output row: unit j, gate p
  int p = r & 3, j = r >> 2;
  int src = p * 1024 + j;
  const float* wi = wi0 + (size_t)src * 319;
  const float* wh = wh0 + (size_t)src * 1024;
  uint16_t* dst = W0c + (size_t)r * 1344;
  for (int k = threadIdx.x; k < 1344; k += 256) {
    float v;
    if (k < 319) v = wi[k];
    else if (k == 319) v = 0.0f;
    else v = wh[k - 320];
    dst[k] = f2bf(v);
  }
  if (threadIdx.x == 0) b0[r] = bi0[src] + bh0[src];
}

__global__ __launch_bounds__(256) void k_prep_w1(
    const float* __restrict__ wi1, const float* __restrict__ bi1,
    const float* __restrict__ wh1, const float* __restrict__ bh1,
    uint16_t* __restrict__ W1c, float* __restrict__ b1) {
  int r = blockIdx.x;
  int p = r & 3, j = r >> 2;
  int src = p * 1024 + j;
  const float* wi = wi1 + (size_t)src * 1024;
  const float* wh = wh1 + (size_t)src * 1024;
  uint16_t* dst = W1c + (size_t)r * 2048;
  for (int k = threadIdx.x; k < 2048; k += 256) {
    float v = (k < 1024) ? wi[k] : wh[k - 1024];
    dst[k] = f2bf(v);
  }
  if (threadIdx.x == 0) b1[r] = bi1[src] + bh1[src];
}

__global__ __launch_bounds__(256) void k_init(
    const float* __restrict__ h_init, const float* __restrict__ c_init,
    uint16_t* __restrict__ h_slot, float* __restrict__ c_state,
    uint32_t* __restrict__ sync) {
  int i = blockIdx.x * 256 + threadIdx.x;  // 262144 = 256*1024
  h_slot[i] = f2bf(h_init[i]);             // layer0 slice of h_init
  c_state[i] = c_init[i];
#pragma unroll
  for (int q = 0; q < 9; ++q) {            // zero arrive(131072)+go(2097152)
    size_t idx = (size_t)q * 262144 + i;
    if (idx < 2228224) sync[idx] = 0;
  }
}

// ---------------- embedding + concat -> x_bf ----------------
__global__ __launch_bounds__(256) void k_embed(
    const int* __restrict__ tokens, const float* __restrict__ casing,
    const float* __restrict__ pos, const float* __restrict__ emb,
    uint16_t* __restrict__ x_bf) {
  int row = blockIdx.x * 4 + (threadIdx.x >> 6);  // (t*256+b)
  int l = threadIdx.x & 63;
  int tok = tokens[row];
  const float* er = emb + (size_t)tok * 300;
  uint16_t* xr = x_bf + (size_t)row * 320;
#pragma unroll
  for (int c0 = 0; c0 < 320; c0 += 64) {
    int c = c0 + l;
    float v;
    if (c < 300) v = er[c];
    else if (c < 307) v = casing[(size_t)row * 7 + (c - 300)];
    else if (c < 319) v = pos[(size_t)row * 12 + (c - 307)];
    else v = 0.0f;
    xr[c] = f2bf(v);
  }
}

// ---------------- persistent layer0 chunk (CH steps, 1 launch) ----------------
// Grid 512 = 2 blocks/CU.  Block = (Mb 64-row batch tile, Nb 32-col tile),
// XCD-chunked swizzle.  Per step: R9's proven K-loop (4 waves 2x2 over
// (32M,16N), vmcnt(4) ring, one s_barrier/iter), fused cell epilogue (c in
// regs), fresh-slot h publish via agent atomic u32 pairs, then the
// sense-tree barrier (group = lid&3; reducer = member 0; private go lines).
__global__ __launch_bounds__(256, 2) void k_l0chunk(
    const uint16_t* __restrict__ x_bf, const uint16_t* __restrict__ W0c,
    const float* __restrict__ b0, uint16_t* __restrict__ h0buf,
    uint16_t* __restrict__ c0buf, float* __restrict__ c_st,
    uint32_t* __restrict__ arrive, uint32_t* __restrict__ goflags,
    int t0, int CH, int in_s0) {
  __shared__ __align__(16) uint16_t As[4][2048];  // 64 rows x 32 k
  __shared__ __align__(16) uint16_t Bs[4][1024];  // 32 rows x 32 k
  __shared__ __align__(16) float epi[4][16][20];
  const int tid = threadIdx.x;
  const int w = tid >> 6, l = tid & 63;
  const int wr = w >> 1, wc = w & 1;
  const int lid = (blockIdx.x & 7) * 64 + (blockIdx.x >> 3);  // bijective
  const int Mb = (lid & 3) * 64;    // batch tile (64 rows)
  const int Nb = (lid >> 2) * 32;   // col tile (32 interleaved cols)

  const int sc = (l & 3) ^ ((l >> 3) & 3);
  const int arow = Mb + w * 16 + (l >> 2);  // A row this lane stages
  const uint16_t* wrow =
      W0c + (size_t)(Nb + (w & 1) * 16 + (l >> 2)) * 1344 + sc * 8;

  // 2 cells/thread, fixed across steps; c in registers
  const int jbase = (Nb + wc * 16) >> 2;
  const int rr = l >> 2, jj = l & 3;
  int gidx2[2];
  float creg[2];
#pragma unroll
  for (int m = 0; m < 2; ++m) {
    int bg = Mb + wr * 32 + m * 16 + rr;
    gidx2[m] = bg * 1024 + jbase + jj;
    creg[m] = c_st[gidx2[m]];
  }

  for (int tl = 0; tl < CH; ++tl) {
    const int t = t0 + tl;
    const int is = (tl > 0) ? (tl - 1) : in_s0;
    const uint16_t* xrow = x_bf + ((size_t)t * 256 + arow) * 320 + sc * 8;
    const uint16_t* hrow =
        h0buf + (size_t)is * SLOT + (size_t)arow * 1024 + sc * 8;
    auto stage = [&](int kt, int buf) {
      int kg = kt * 32;
      const uint16_t* sA = (kt < 10) ? (xrow + kg) : (hrow + (kg - 320));
      gload_lds16(sA, &As[buf][w * 512]);
      gload_lds16(wrow + kg, &Bs[buf][(w & 1) * 512]);
    };

    f32x4 acc[2] = {};
    stage(0, 0);
    stage(1, 1);
    stage(2, 2);
    for (int kt = 0; kt < 42; ++kt) {
      __builtin_amdgcn_sched_barrier(0);
      if (kt < 40) asm volatile("s_waitcnt vmcnt(4)" ::: "memory");
      else if (kt == 40) asm volatile("s_waitcnt vmcnt(2)" ::: "memory");
      else asm volatile("s_waitcnt vmcnt(0)" ::: "memory");
      __builtin_amdgcn_s_barrier();
      __builtin_amdgcn_sched_barrier(0);
      if (kt < 39) stage(kt + 3, (kt + 3) & 3);
      const uint16_t* Ab = As[kt & 3];
      const uint16_t* Bb = Bs[kt & 3];
      bf16x8 a0 = lds_frag(Ab, wr * 32 + (l & 15), l >> 4);
      bf16x8 a1 = lds_frag(Ab, wr * 32 + 16 + (l & 15), l >> 4);
      bf16x8 q0 = lds_frag(Bb, wc * 16 + (l & 15), l >> 4);
      acc[0] = mfma16(a0, q0, acc[0]);
      acc[1] = mfma16(a1, q0, acc[1]);
    }

    // fused LSTM cell epilogue; h -> fresh slot tl (agent atomic u32 pairs)
    uint32_t* hc = (uint32_t*)(h0buf + (size_t)tl * SLOT);
    uint32_t* cc = (uint32_t*)(c0buf + (size_t)tl * SLOT);
#pragma unroll
    for (int m = 0; m < 2; ++m) {
#pragma unroll
      for (int r = 0; r < 4; ++r)
        epi[w][(l >> 4) * 4 + r][l & 15] = acc[m][r];
      asm volatile("s_waitcnt lgkmcnt(0)" ::: "memory");
      {
        f32x4 q = *(const f32x4*)&epi[w][rr][jj * 4];
        f32x4 bv = *(const f32x4*)&b0[(jbase + jj) * 4];
        float vi = sigmoidf_(q[0] + bv[0]);
        float vf = sigmoidf_(q[1] + bv[1]);
        float vo = sigmoidf_(q[2] + bv[2]);
        float vg = tanhf_(q[3] + bv[3]);
        float cn = vf * creg[m] + vi * vg;
        creg[m] = cn;
        float hh = vo * tanhf_(cn);
        uint32_t hu = f2bf(hh), cu = f2bf(cn);
        uint32_t hp = hu | ((uint32_t)__shfl_xor((int)hu, 1) << 16);
        uint32_t cp = cu | ((uint32_t)__shfl_xor((int)cu, 1) << 16);
        if ((l & 1) == 0) {
          size_t pidx = (size_t)(gidx2[m] >> 1);
          __hip_atomic_store(hc + pidx, hp, __ATOMIC_RELAXED,
                             __HIP_MEMORY_SCOPE_AGENT);
          cc[pidx] = cp;
        }
      }
      asm volatile("s_waitcnt lgkmcnt(0)" ::: "memory");
    }

    // sense-tree inter-step barrier, per Mb-group (128 blocks):
    //   arrive: 1 release store/block (distinct words, 8 lines/group)
    //   reduce: member-0 block scans its group's 128 flags (1 load/thread)
    //   fanout: 128 release stores to per-waiter PRIVATE 64B lines
    //   wait:   tid 0 polls its own line, relaxed (no sharing, no RMW)
    if (tl + 1 < CH) {
      __syncthreads();  // drains vmcnt -> all h stores at coherence point
      const int g = lid & 3, mem = lid >> 2;
      uint32_t* arr = arrive + ((size_t)t * 4 + g) * 128;
      if (tid == 0)
        __hip_atomic_store(&arr[mem], 1u, __ATOMIC_RELEASE,
                           __HIP_MEMORY_SCOPE_AGENT);
      if (mem == 0) {
        int spins = 0;
        for (;;) {
          uint32_t v = 1u;
          if (tid < 128)
            v = __hip_atomic_load(&arr[tid], __ATOMIC_RELAXED,
                                  __HIP_MEMORY_SCOPE_AGENT);
          if (__syncthreads_and((int)(v != 0))) break;
          if (++spins > 50000) break;  // bounded: bug -> wrong, not hung
          __builtin_amdgcn_s_sleep(1);
        }
        if (tid < 128)
          __hip_atomic_store(
              goflags + ((size_t)t * 512 + (size_t)tid * 4 + g) * 16, 1u,
              __ATOMIC_RELEASE, __HIP_MEMORY_SCOPE_AGENT);
        __syncthreads();
      } else {
        if (tid == 0) {
          uint32_t* gol = goflags + ((size_t)t * 512 + lid) * 16;
          int spins = 0;
          while (__hip_atomic_load(gol, __ATOMIC_RELAXED,
                                   __HIP_MEMORY_SCOPE_AGENT) == 0u) {
            __builtin_amdgcn_s_sleep(1);
            if (++spins > 50000) break;
          }
        }
        __syncthreads();
      }
      __builtin_amdgcn_sched_barrier(0);
    }
  }
#pragma unroll
  for (int m = 0; m < 2; ++m) c_st[gidx2[m]] = creg[m];
}

// ---------------- layer1 GEMM over one chunk ----------------
// rows = CH*256; A row (t,b) = [h0(t,b) | h0(t,255-b)]  (slot tl of h0buf).
// tile 128x128, 4 waves (2x2) x (4x4 frags), fused cell epilogue.
// 1-D grid 64*CH, XCD-chunked swizzle: XCD k owns N-panels [4k,4k+4).
__global__ __launch_bounds__(256) void k_l1gemm(
    const uint16_t* __restrict__ h0buf, const uint16_t* __restrict__ W1c,
    const float* __restrict__ b1, const uint16_t* __restrict__ c0buf,
    uint16_t* __restrict__ h1buf) {
  __shared__ __align__(16) uint16_t As[128 * 32];
  __shared__ __align__(16) uint16_t Bs[128 * 32];
  __shared__ __align__(16) float epi[4][16][68];
  int tid = threadIdx.x;
  int w = tid >> 6, l = tid & 63;
  int wr = w >> 1, wc = w & 1;
  uint32_t G = gridDim.x;          // 64*CH (divisible by 8)
  uint32_t cpx = G >> 3;
  uint32_t lid = (blockIdx.x & 7) * cpx + (blockIdx.x >> 3);  // bijective
  uint32_t yyTot = G >> 5;         // 2*CH row-tiles per N-panel
  uint32_t nb = lid / yyTot;       // N-panel 0..31
  uint32_t yy = lid - nb * yyTot;  // row tile 0..2CH-1
  int Nb = (int)nb * 128;
  int tl = (int)(yy >> 1);
  int bbase = (int)(yy & 1) * 128;
  const uint16_t* hrow = h0buf + (size_t)tl * SLOT;
  const uint16_t* c0s = c0buf + (size_t)tl * SLOT;
  uint16_t* h1s = h1buf + (size_t)tl * SLOT;
  f32x4 acc[4][4] = {};

  int sc = (l & 3) ^ ((l >> 3) & 3);
  int srow0 = (w * 2 + 0) * 16 + (l >> 2);
  int srow1 = (w * 2 + 1) * 16 + (l >> 2);
  const uint16_t* hA0n = hrow + (size_t)(bbase + srow0) * 1024;
  const uint16_t* hA0f = hrow + (size_t)(255 - (bbase + srow0)) * 1024;
  const uint16_t* hA1n = hrow + (size_t)(bbase + srow1) * 1024;
  const uint16_t* hA1f = hrow + (size_t)(255 - (bbase + srow1)) * 1024;
  const uint16_t* wB0 = W1c + (size_t)(Nb + srow0) * 2048;
  const uint16_t* wB1 = W1c + (size_t)(Nb + srow1) * 2048;
  uint16_t* AsW0 = As + (w * 2 + 0) * 512;
  uint16_t* AsW1 = As + (w * 2 + 1) * 512;
  uint16_t* BsW0 = Bs + (w * 2 + 0) * 512;
  uint16_t* BsW1 = Bs + (w * 2 + 1) * 512;

  for (int kt = 0; kt < 64; ++kt) {
    int kg = kt * 32 + sc * 8;
    const uint16_t* sA0 = (kg < 1024) ? (hA0n + kg) : (hA0f + (kg - 1024));
    const uint16_t* sA1 = (kg < 1024) ? (hA1n + kg) : (hA1f + (kg - 1024));
    gload_lds16(sA0, AsW0);
    gload_lds16(sA1, AsW1);
    gload_lds16(wB0 + kg, BsW0);
    gload_lds16(wB1 + kg, BsW1);
    __syncthreads();
    bf16x8 a[4], q[4];
#pragma unroll
    for (int m = 0; m < 4; ++m) a[m] = lds_frag(As, wr * 64 + m * 16 + (l & 15), l >> 4);
#pragma unroll
    for (int n = 0; n < 4; ++n) q[n] = lds_frag(Bs, wc * 64 + n * 16 + (l & 15), l >> 4);
#pragma unroll
    for (int m = 0; m < 4; ++m)
#pragma unroll
      for (int n = 0; n < 4; ++n) acc[m][n] = mfma16(a[m], q[n], acc[m][n]);
    __syncthreads();
  }

  int jbase = (Nb + wc * 64) >> 2;
#pragma unroll
  for (int m = 0; m < 4; ++m) {
#pragma unroll
    for (int n = 0; n < 4; ++n)
#pragma unroll
      for (int r = 0; r < 4; ++r)
        epi[w][(l >> 4) * 4 + r][n * 16 + (l & 15)] = acc[m][n][r];
    asm volatile("s_waitcnt lgkmcnt(0)" ::: "memory");
#pragma unroll
    for (int it = 0; it < 4; ++it) {
      int pp = it * 64 + l;
      int rr = pp >> 4, j = pp & 15;
      f32x4 q = *(const f32x4*)&epi[w][rr][j * 4];
      f32x4 bv = *(const f32x4*)&b1[(size_t)(jbase + j) * 4];
      float vi = sigmoidf_(q[0] + bv[0]);
      float vf = sigmoidf_(q[1] + bv[1]);
      float vo = sigmoidf_(q[2] + bv[2]);
      float vg = tanhf_(q[3] + bv[3]);
      int rowl = wr * 64 + m * 16 + rr;
      int b = bbase + rowl;
      int jg = jbase + j;
      float c0v = bf2f(c0s[(size_t)(255 - b) * 1024 + jg]);
      float cn = vf * c0v + vi * vg;
      float hh = vo * tanhf_(cn);
      h1s[(size_t)b * 1024 + jg] = f2bf(hh);
    }
    asm volatile("s_waitcnt lgkmcnt(0)" ::: "memory");
  }
}

// ---------------- decoder over one chunk ----------------
__global__ __launch_bounds__(256) void k_decode(
    const uint16_t* __restrict__ h0buf, const uint16_t* __restrict__ h1buf,
    const float* __restrict__ dec_w, const float* __restrict__ dec_b,
    float* __restrict__ out, int t0) {
  int rowl = blockIdx.x * 4 + (threadIdx.x >> 6);  // chunk-local row
  int l = threadIdx.x & 63;
  int tl = rowl >> 8, b = rowl & 255;
  const uint16_t* h0 = h0buf + (size_t)tl * SLOT + (size_t)b * 1024;
  const uint16_t* h1 = h1buf + (size_t)tl * SLOT + (size_t)b * 1024;
  float acc[13];
#pragma unroll
  for (int c = 0; c < 13; ++c) acc[c] = 0.0f;
#pragma unroll
  for (int part = 0; part < 2; ++part) {
    const uint16_t* h = part ? h1 : h0;
    const float* wb = dec_w + part * 1024 + (size_t)l * 16;
    float hv[16];
    const bf16x8* hp = (const bf16x8*)(h + l * 16);
    bf16x8 v0 = hp[0];
    bf16x8 v1 = hp[1];
#pragma unroll
    for (int jj = 0; jj < 8; ++jj) {
      hv[jj] = bf2f((uint16_t)v0[jj]);
      hv[8 + jj] = bf2f((uint16_t)v1[jj]);
    }
#pragma unroll
    for (int c = 0; c < 13; ++c) {
      const float* wc = wb + (size_t)c * 2048;
      float s = 0.0f;
#pragma unroll
      for (int jj = 0; jj < 16; ++jj) s += hv[jj] * wc[jj];
      acc[c] += s;
    }
  }
#pragma unroll
  for (int c = 0; c < 13; ++c) {
    float v = acc[c];
#pragma unroll
    for (int off = 32; off > 0; off >>= 1) v += __shfl_xor(v, off, 64);
    acc[c] = v;
  }
  if (l == 0) {
    int t = t0 + tl;
    float* orow = out + ((size_t)t * 256 + b) * 13;
#pragma unroll
    for (int c = 0; c < 13; ++c) orow[c] = acc[c] + dec_b[c];
  }
}

// ---------------- host ----------------
extern "C" void kernel_launch(void* const* d_in, const int* in_sizes, int n_in,
                              void* d_out, int out_size, void* d_ws, size_t ws_size,
                              hipStream_t stream) {
  const int* tokens = (const int*)d_in[0];
  const float* casing = (const float*)d_in[1];
  const float* pos = (const float*)d_in[2];
  const float* emb = (const float*)d_in[3];
  const float* wi0 = (const float*)d_in[4];
  const float* bi0 = (const float*)d_in[5];
  const float* wh0 = (const float*)d_in[6];
  const float* bh0 = (const float*)d_in[7];
  const float* wi1 = (const float*)d_in[8];
  const float* bi1 = (const float*)d_in[9];
  const float* wh1 = (const float*)d_in[10];
  const float* bh1 = (const float*)d_in[11];
  const float* dec_w = (const float*)d_in[12];
  const float* dec_b = (const float*)d_in[13];
  const float* h_init = (const float*)d_in[14];
  const float* c_init = (const float*)d_in[15];
  float* out = (float*)d_out;
  (void)in_sizes; (void)n_in; (void)out_size;

  char* ws = (char*)d_ws;
  size_t off = 0;
  auto alloc = [&](size_t bytes) {
    char* p = ws + off;
    off += (bytes + 255) & ~(size_t)255;
    return p;
  };
  // fixed buffers (~78 MB)
  uint16_t* W0c = (uint16_t*)alloc(4096ull * 1344 * 2);
  float* b0 = (float*)alloc(4096 * 4);
  uint16_t* W1c = (uint16_t*)alloc(4096ull * 2048 * 2);
  float* b1 = (float*)alloc(4096 * 4);
  uint16_t* x_bf = (uint16_t*)alloc(65536ull * 320 * 2);
  float* c_st = (float*)alloc(SLOT * 4);
  uint32_t* sync = (uint32_t*)alloc(2228224ull * 4);  // arrive + go flags
  uint32_t* arrive = sync;               // 256 steps x 4 groups x 128
  uint32_t* goflags = sync + 131072;     // 256 steps x 512 blocks x 16

  // chunk size: (CH+1) + CH + CH slots of SLOT*2 bytes
  const size_t SB = SLOT * 2;  // 524288, 256-aligned
  int CH = 0;
  for (int c = 64; c >= 2; c >>= 1) {
    if (off + (size_t)(3 * c + 1) * SB + 4096 <= ws_size) { CH = c; break; }
  }
  if (CH == 0) return;  // ws too small (diagnostic: poisoned output)
  uint16_t* h0buf = (uint16_t*)alloc((size_t)(CH + 1) * SB);  // slot CH = h_init
  uint16_t* c0buf = (uint16_t*)alloc((size_t)CH * SB);
  uint16_t* h1buf = (uint16_t*)alloc((size_t)CH * SB);

  k_prep_w0<<<4096, 256, 0, stream>>>(wi0, bi0, wh0, bh0, W0c, b0);
  k_prep_w1<<<4096, 256, 0, stream>>>(wi1, bi1, wh1, bh1, W1c, b1);
  k_embed<<<16384, 256, 0, stream>>>(tokens, casing, pos, emb, x_bf);
  k_init<<<1024, 256, 0, stream>>>(h_init, c_init, h0buf + (size_t)CH * SLOT,
                                   c_st, sync);

  for (int t0 = 0; t0 < 256; t0 += CH) {
    // input slot for tl==0: h_init slot (CH) at t0==0, else prev chunk's
    // last slot (CH-1); within a launch slot CH-1 is read at tl==0 and only
    // rewritten at tl==CH-1 (barriers order it).
    int in_s0 = (t0 == 0) ? CH : CH - 1;
    k_l0chunk<<<512, 256, 0, stream>>>(x_bf, W0c, b0, h0buf, c0buf, c_st,
                                       arrive, goflags, t0, CH, in_s0);
    k_l1gemm<<<64 * CH, 256, 0, stream>>>(h0buf, W1c, b1, c0buf, h1buf);
    k_decode<<<CH * 64, 256, 0, stream>>>(h0buf, h1buf, dec_w, dec_b, out, t0);
  }
}

// Round 13
// 5997.561 us; speedup vs baseline: 1.9203x; 1.8029x over previous
//
#include <hip/hip_runtime.h>
#include <stdint.h>

// ---------------------------------------------------------------------------
// AWD-LSTM eval forward.  T=256, B=256, H=1024, FEAT=319 (=300+7+12), C=13.
// Layer1's recurrent carry is ignored by the reference -> only layer0 is
// sequential; layer1+decoder are parallel over rows.
// Round 13: R9 structure (best: 6312 us).  Six in-kernel barrier designs all
// cost 22-38 us/step vs the launch path's 17-19 -> persistent layer0 closed;
// cross-XCD sync ~10-15 us is a chip-structural floor.  This round: l1gemm
// occupancy only -- (1) union epilogue scratch onto stage LDS (33->17.4 KB),
// (2) __launch_bounds__(256,3) -> 3 blocks/CU so co-resident blocks hide the
// per-iter barrier drain (m114 mechanism that powers m97's 874-912 TF).
// GEMMs: bf16 MFMA 16x16x32, f32 accum; weights gate-interleaved
// (col 4j+p = gate p of unit j) so the LSTM cell fuses into the epilogue.
// ---------------------------------------------------------------------------

typedef __attribute__((ext_vector_type(8))) short bf16x8;
typedef __attribute__((ext_vector_type(4))) float f32x4;

#define SLOT 262144ull  // 256*1024 elements per (B,H) slab

__device__ __forceinline__ uint16_t f2bf(float f) {
  uint32_t u = __float_as_uint(f);
  u += 0x7fffu + ((u >> 16) & 1u);
  return (uint16_t)(u >> 16);
}
__device__ __forceinline__ float bf2f(uint16_t h) {
  return __uint_as_float(((uint32_t)h) << 16);
}
__device__ __forceinline__ float sigmoidf_(float x) {
  return __builtin_amdgcn_rcpf(1.0f + __expf(-x));
}
__device__ __forceinline__ float tanhf_(float x) {
  return 1.0f - 2.0f * __builtin_amdgcn_rcpf(__expf(2.0f * x) + 1.0f);
}
__device__ __forceinline__ void gload_lds16(const void* g, void* l) {
  __builtin_amdgcn_global_load_lds(
      (const __attribute__((address_space(1))) void*)g,
      (__attribute__((address_space(3))) void*)l, 16, 0, 0);
}
// LDS tile: row-major [rows][32 k] bf16; four 16B chunks of each row stored
// permuted: chunk_pos = chunk ^ ((row>>1)&3)  -> ~2-way banks
__device__ __forceinline__ bf16x8 lds_frag(const uint16_t* base, int row, int kc) {
  const uint16_t* p = base + row * 32 + ((kc ^ ((row >> 1) & 3)) << 3);
  return *(const bf16x8*)p;
}
__device__ __forceinline__ f32x4 mfma16(bf16x8 a, bf16x8 b, f32x4 c) {
  return __builtin_amdgcn_mfma_f32_16x16x32_bf16(a, b, c, 0, 0, 0);
}

// ---------------- weight prep ----------------
__global__ __launch_bounds__(256) void k_prep_w0(
    const float* __restrict__ wi0, const float* __restrict__ bi0,
    const float* __restrict__ wh0, const float* __restrict__ bh0,
    uint16_t* __restrict__ W0c, float* __restrict__ b0) {
  int r = blockIdx.x;            // interleaved output row: unit j, gate p
  int p = r & 3, j = r >> 2;
  int src = p * 1024 + j;
  const float* wi = wi0 + (size_t)src * 319;
  const float* wh = wh0 + (size_t)src * 1024;
  uint16_t* dst = W0c + (size_t)r * 1344;
  for (int k = threadIdx.x; k < 1344; k += 256) {
    float v;
    if (k < 319) v = wi[k];
    else if (k == 319) v = 0.0f;
    else v = wh[k - 320];
    dst[k] = f2bf(v);
  }
  if (threadIdx.x == 0) b0[r] = bi0[src] + bh0[src];
}

__global__ __launch_bounds__(256) void k_prep_w1(
    const float* __restrict__ wi1, const float* __restrict__ bi1,
    const float* __restrict__ wh1, const float* __restrict__ bh1,
    uint16_t* __restrict__ W1c, float* __restrict__ b1) {
  int r = blockIdx.x;
  int p = r & 3, j = r >> 2;
  int src = p * 1024 + j;
  const float* wi = wi1 + (size_t)src * 1024;
  const float* wh = wh1 + (size_t)src * 1024;
  uint16_t* dst = W1c + (size_t)r * 2048;
  for (int k = threadIdx.x; k < 2048; k += 256) {
    float v = (k < 1024) ? wi[k] : wh[k - 1024];
    dst[k] = f2bf(v);
  }
  if (threadIdx.x == 0) b1[r] = bi1[src] + bh1[src];
}

__global__ __launch_bounds__(256) void k_init(
    const float* __restrict__ h_init, const float* __restrict__ c_init,
    uint16_t* __restrict__ h_slot, float* __restrict__ c_state) {
  int i = blockIdx.x * 256 + threadIdx.x;  // 262144 = 256*1024
  h_slot[i] = f2bf(h_init[i]);             // layer0 slice of h_init
  c_state[i] = c_init[i];
}

// ---------------- embedding + concat -> x_bf ----------------
__global__ __launch_bounds__(256) void k_embed(
    const int* __restrict__ tokens, const float* __restrict__ casing,
    const float* __restrict__ pos, const float* __restrict__ emb,
    uint16_t* __restrict__ x_bf) {
  int row = blockIdx.x * 4 + (threadIdx.x >> 6);  // (t*256+b)
  int l = threadIdx.x & 63;
  int tok = tokens[row];
  const float* er = emb + (size_t)tok * 300;
  uint16_t* xr = x_bf + (size_t)row * 320;
#pragma unroll
  for (int c0 = 0; c0 < 320; c0 += 64) {
    int c = c0 + l;
    float v;
    if (c < 300) v = er[c];
    else if (c < 307) v = casing[(size_t)row * 7 + (c - 300)];
    else if (c < 319) v = pos[(size_t)row * 12 + (c - 307)];
    else v = 0.0f;
    xr[c] = f2bf(v);
  }
}

// ---------------- layer0 sequential step (R9 verbatim) ----------------
// GEMM [256 x 1344] @ [4096 x 1344]^T, tile 64M x 32N, grid 512 (2 blocks/CU),
// 4 waves 2x2 over (32M,16N).  4-buffer ring, vmcnt(4), one barrier/iter.
__global__ __launch_bounds__(256, 2) void k_step(
    const uint16_t* __restrict__ x_t, const uint16_t* __restrict__ W0c,
    const float* __restrict__ b0, const uint16_t* __restrict__ h_in,
    uint16_t* __restrict__ h_out, uint16_t* __restrict__ c0_out,
    float* __restrict__ c_state) {
  __shared__ __align__(16) uint16_t As[4][2048];  // 64 rows x 32 k
  __shared__ __align__(16) uint16_t Bs[4][1024];  // 32 rows x 32 k
  __shared__ __align__(16) float epi[4][16][20];
  int tid = threadIdx.x;
  int w = tid >> 6, l = tid & 63;
  int wr = w >> 1, wc = w & 1;
  int lid = (blockIdx.x & 7) * 64 + (blockIdx.x >> 3);  // bijective (512=8*64)
  int Mb = (lid & 3) * 64;    // batch tile (64 rows)
  int Nb = (lid >> 2) * 32;   // output-col tile (32 interleaved cols)
  f32x4 acc[2] = {};

  int sc = (l & 3) ^ ((l >> 3) & 3);  // global chunk for this lane's LDS slot
  const uint16_t* xrow = x_t + (size_t)(Mb + w * 16 + (l >> 2)) * 320 + sc * 8;
  const uint16_t* hrow = h_in + (size_t)(Mb + w * 16 + (l >> 2)) * 1024 + sc * 8;
  const uint16_t* wrow =
      W0c + (size_t)(Nb + (w & 1) * 16 + (l >> 2)) * 1344 + sc * 8;

  auto stage = [&](int kt, int buf) {
    int kg = kt * 32;
    const uint16_t* sA = (kt < 10) ? (xrow + kg) : (hrow + (kg - 320));
    gload_lds16(sA, &As[buf][w * 512]);
    gload_lds16(wrow + kg, &Bs[buf][(w & 1) * 512]);
  };

  stage(0, 0);
  stage(1, 1);
  stage(2, 2);
  for (int kt = 0; kt < 42; ++kt) {
    __builtin_amdgcn_sched_barrier(0);
    if (kt < 40) asm volatile("s_waitcnt vmcnt(4)" ::: "memory");
    else if (kt == 40) asm volatile("s_waitcnt vmcnt(2)" ::: "memory");
    else asm volatile("s_waitcnt vmcnt(0)" ::: "memory");
    __builtin_amdgcn_s_barrier();
    __builtin_amdgcn_sched_barrier(0);
    if (kt < 39) stage(kt + 3, (kt + 3) & 3);
    const uint16_t* Ab = As[kt & 3];
    const uint16_t* Bb = Bs[kt & 3];
    bf16x8 a0 = lds_frag(Ab, wr * 32 + (l & 15), l >> 4);
    bf16x8 a1 = lds_frag(Ab, wr * 32 + 16 + (l & 15), l >> 4);
    bf16x8 q0 = lds_frag(Bb, wc * 16 + (l & 15), l >> 4);
    acc[0] = mfma16(a0, q0, acc[0]);
    acc[1] = mfma16(a1, q0, acc[1]);
  }

  // fused LSTM cell epilogue: per wave 32x16 outputs = 2 frags, 2 cells/thread
  int jbase = (Nb + wc * 16) >> 2;
#pragma unroll
  for (int m = 0; m < 2; ++m) {
#pragma unroll
    for (int r = 0; r < 4; ++r)
      epi[w][(l >> 4) * 4 + r][l & 15] = acc[m][r];
    asm volatile("s_waitcnt lgkmcnt(0)" ::: "memory");
    {
      int rr = l >> 2, j = l & 3;
      f32x4 q = *(const f32x4*)&epi[w][rr][j * 4];
      f32x4 bv = *(const f32x4*)&b0[(jbase + j) * 4];
      float vi = sigmoidf_(q[0] + bv[0]);
      float vf = sigmoidf_(q[1] + bv[1]);
      float vo = sigmoidf_(q[2] + bv[2]);
      float vg = tanhf_(q[3] + bv[3]);
      int bg = Mb + wr * 32 + m * 16 + rr;
      int jg = jbase + j;
      size_t sidx = (size_t)bg * 1024 + jg;
      float cold = c_state[sidx];
      float cn = vf * cold + vi * vg;
      float hh = vo * tanhf_(cn);
      c_state[sidx] = cn;
      c0_out[sidx] = f2bf(cn);
      h_out[sidx] = f2bf(hh);
    }
    asm volatile("s_waitcnt lgkmcnt(0)" ::: "memory");
  }
}

// ---------------- layer1 GEMM over one chunk ----------------
// rows = CH*256; A row (t,b) = [h0(t,b) | h0(t,255-b)]  (slot tl of h0buf).
// tile 128x128, 4 waves (2x2) x (4x4 frags), fused cell epilogue.
// 1-D grid 64*CH, XCD-chunked swizzle: XCD k owns N-panels [4k,4k+4).
// LDS: stage (16 KB) UNIONed with epilogue scratch (17.4 KB) -> 17.4 KB
// total; __launch_bounds__(256,3) -> 3 blocks/CU co-resident so one block's
// MFMA hides another's per-iter barrier drain (m114).
__global__ __launch_bounds__(256, 3) void k_l1gemm(
    const uint16_t* __restrict__ h0buf, const uint16_t* __restrict__ W1c,
    const float* __restrict__ b1, const uint16_t* __restrict__ c0buf,
    uint16_t* __restrict__ h1buf) {
  __shared__ __align__(16) char smem[17408];  // max(As+Bs=16384, epi=17408)
  uint16_t* As = (uint16_t*)smem;             // 128x32 bf16 = 8192 B
  uint16_t* Bs = (uint16_t*)(smem + 8192);    // 128x32 bf16 = 8192 B
  float* epif = (float*)smem;                 // [4][16][68] f32 = 17408 B
  int tid = threadIdx.x;
  int w = tid >> 6, l = tid & 63;
  int wr = w >> 1, wc = w & 1;
  uint32_t G = gridDim.x;          // 64*CH (divisible by 8)
  uint32_t cpx = G >> 3;
  uint32_t lid = (blockIdx.x & 7) * cpx + (blockIdx.x >> 3);  // bijective
  uint32_t yyTot = G >> 5;         // 2*CH row-tiles per N-panel
  uint32_t nb = lid / yyTot;       // N-panel 0..31
  uint32_t yy = lid - nb * yyTot;  // row tile 0..2CH-1
  int Nb = (int)nb * 128;
  int tl = (int)(yy >> 1);
  int bbase = (int)(yy & 1) * 128;
  const uint16_t* hrow = h0buf + (size_t)tl * SLOT;
  const uint16_t* c0s = c0buf + (size_t)tl * SLOT;
  uint16_t* h1s = h1buf + (size_t)tl * SLOT;
  f32x4 acc[4][4] = {};

  int sc = (l & 3) ^ ((l >> 3) & 3);
  int srow0 = (w * 2 + 0) * 16 + (l >> 2);
  int srow1 = (w * 2 + 1) * 16 + (l >> 2);
  const uint16_t* hA0n = hrow + (size_t)(bbase + srow0) * 1024;
  const uint16_t* hA0f = hrow + (size_t)(255 - (bbase + srow0)) * 1024;
  const uint16_t* hA1n = hrow + (size_t)(bbase + srow1) * 1024;
  const uint16_t* hA1f = hrow + (size_t)(255 - (bbase + srow1)) * 1024;
  const uint16_t* wB0 = W1c + (size_t)(Nb + srow0) * 2048;
  const uint16_t* wB1 = W1c + (size_t)(Nb + srow1) * 2048;
  uint16_t* AsW0 = As + (w * 2 + 0) * 512;
  uint16_t* AsW1 = As + (w * 2 + 1) * 512;
  uint16_t* BsW0 = Bs + (w * 2 + 0) * 512;
  uint16_t* BsW1 = Bs + (w * 2 + 1) * 512;

  for (int kt = 0; kt < 64; ++kt) {
    int kg = kt * 32 + sc * 8;
    const uint16_t* sA0 = (kg < 1024) ? (hA0n + kg) : (hA0f + (kg - 1024));
    const uint16_t* sA1 = (kg < 1024) ? (hA1n + kg) : (hA1f + (kg - 1024));
    gload_lds16(sA0, AsW0);
    gload_lds16(sA1, AsW1);
    gload_lds16(wB0 + kg, BsW0);
    gload_lds16(wB1 + kg, BsW1);
    __syncthreads();
    bf16x8 a[4], q[4];
#pragma unroll
    for (int m = 0; m < 4; ++m) a[m] = lds_frag(As, wr * 64 + m * 16 + (l & 15), l >> 4);
#pragma unroll
    for (int n = 0; n < 4; ++n) q[n] = lds_frag(Bs, wc * 64 + n * 16 + (l & 15), l >> 4);
#pragma unroll
    for (int m = 0; m < 4; ++m)
#pragma unroll
      for (int n = 0; n < 4; ++n) acc[m][n] = mfma16(a[m], q[n], acc[m][n]);
    __syncthreads();
  }
  // last loop iter ends with __syncthreads -> safe to reuse smem as epi

  int jbase = (Nb + wc * 64) >> 2;
#pragma unroll
  for (int m = 0; m < 4; ++m) {
#pragma unroll
    for (int n = 0; n < 4; ++n)
#pragma unroll
      for (int r = 0; r < 4; ++r)
        epif[((size_t)w * 16 + (l >> 4) * 4 + r) * 68 + n * 16 + (l & 15)] =
            acc[m][n][r];
    asm volatile("s_waitcnt lgkmcnt(0)" ::: "memory");
#pragma unroll
    for (int it = 0; it < 4; ++it) {
      int pp = it * 64 + l;
      int rr = pp >> 4, j = pp & 15;
      f32x4 q = *(const f32x4*)&epif[((size_t)w * 16 + rr) * 68 + j * 4];
      f32x4 bv = *(const f32x4*)&b1[(size_t)(jbase + j) * 4];
      float vi = sigmoidf_(q[0] + bv[0]);
      float vf = sigmoidf_(q[1] + bv[1]);
      float vo = sigmoidf_(q[2] + bv[2]);
      float vg = tanhf_(q[3] + bv[3]);
      int rowl = wr * 64 + m * 16 + rr;
      int b = bbase + rowl;
      int jg = jbase + j;
      float c0v = bf2f(c0s[(size_t)(255 - b) * 1024 + jg]);
      float cn = vf * c0v + vi * vg;
      float hh = vo * tanhf_(cn);
      h1s[(size_t)b * 1024 + jg] = f2bf(hh);
    }
    asm volatile("s_waitcnt lgkmcnt(0)" ::: "memory");
  }
}

// ---------------- decoder over one chunk ----------------
__global__ __launch_bounds__(256) void k_decode(
    const uint16_t* __restrict__ h0buf, const uint16_t* __restrict__ h1buf,
    const float* __restrict__ dec_w, const float* __restrict__ dec_b,
    float* __restrict__ out, int t0) {
  int rowl = blockIdx.x * 4 + (threadIdx.x >> 6);  // chunk-local row
  int l = threadIdx.x & 63;
  int tl = rowl >> 8, b = rowl & 255;
  const uint16_t* h0 = h0buf + (size_t)tl * SLOT + (size_t)b * 1024;
  const uint16_t* h1 = h1buf + (size_t)tl * SLOT + (size_t)b * 1024;
  float acc[13];
#pragma unroll
  for (int c = 0; c < 13; ++c) acc[c] = 0.0f;
#pragma unroll
  for (int part = 0; part < 2; ++part) {
    const uint16_t* h = part ? h1 : h0;
    const float* wb = dec_w + part * 1024 + (size_t)l * 16;
    float hv[16];
    const bf16x8* hp = (const bf16x8*)(h + l * 16);
    bf16x8 v0 = hp[0];
    bf16x8 v1 = hp[1];
#pragma unroll
    for (int jj = 0; jj < 8; ++jj) {
      hv[jj] = bf2f((uint16_t)v0[jj]);
      hv[8 + jj] = bf2f((uint16_t)v1[jj]);
    }
#pragma unroll
    for (int c = 0; c < 13; ++c) {
      const float* wc = wb + (size_t)c * 2048;
      float s = 0.0f;
#pragma unroll
      for (int jj = 0; jj < 16; ++jj) s += hv[jj] * wc[jj];
      acc[c] += s;
    }
  }
#pragma unroll
  for (int c = 0; c < 13; ++c) {
    float v = acc[c];
#pragma unroll
    for (int off = 32; off > 0; off >>= 1) v += __shfl_xor(v, off, 64);
    acc[c] = v;
  }
  if (l == 0) {
    int t = t0 + tl;
    float* orow = out + ((size_t)t * 256 + b) * 13;
#pragma unroll
    for (int c = 0; c < 13; ++c) orow[c] = acc[c] + dec_b[c];
  }
}

// ---------------- host ----------------
extern "C" void kernel_launch(void* const* d_in, const int* in_sizes, int n_in,
                              void* d_out, int out_size, void* d_ws, size_t ws_size,
                              hipStream_t stream) {
  const int* tokens = (const int*)d_in[0];
  const float* casing = (const float*)d_in[1];
  const float* pos = (const float*)d_in[2];
  const float* emb = (const float*)d_in[3];
  const float* wi0 = (const float*)d_in[4];
  const float* bi0 = (const float*)d_in[5];
  const float* wh0 = (const float*)d_in[6];
  const float* bh0 = (const float*)d_in[7];
  const float* wi1 = (const float*)d_in[8];
  const float* bi1 = (const float*)d_in[9];
  const float* wh1 = (const float*)d_in[10];
  const float* bh1 = (const float*)d_in[11];
  const float* dec_w = (const float*)d_in[12];
  const float* dec_b = (const float*)d_in[13];
  const float* h_init = (const float*)d_in[14];
  const float* c_init = (const float*)d_in[15];
  float* out = (float*)d_out;
  (void)in_sizes; (void)n_in; (void)out_size;

  char* ws = (char*)d_ws;
  size_t off = 0;
  auto alloc = [&](size_t bytes) {
    char* p = ws + off;
    off += (bytes + 255) & ~(size_t)255;
    return p;
  };
  // fixed buffers (~69 MB)
  uint16_t* W0c = (uint16_t*)alloc(4096ull * 1344 * 2);
  float* b0 = (float*)alloc(4096 * 4);
  uint16_t* W1c = (uint16_t*)alloc(4096ull * 2048 * 2);
  float* b1 = (float*)alloc(4096 * 4);
  uint16_t* x_bf = (uint16_t*)alloc(65536ull * 320 * 2);
  float* c_st = (float*)alloc(SLOT * 4);

  // chunk size: (CH+1) + CH + CH slots of SLOT*2 bytes
  const size_t SB = SLOT * 2;  // 524288, 256-aligned
  int CH = 0;
  for (int c = 64; c >= 2; c >>= 1) {
    if (off + (size_t)(3 * c + 1) * SB + 4096 <= ws_size) { CH = c; break; }
  }
  if (CH == 0) return;  // ws too small (diagnostic: poisoned output)
  uint16_t* h0buf = (uint16_t*)alloc((size_t)(CH + 1) * SB);  // slot CH = h_init
  uint16_t* c0buf = (uint16_t*)alloc((size_t)CH * SB);
  uint16_t* h1buf = (uint16_t*)alloc((size_t)CH * SB);

  k_prep_w0<<<4096, 256, 0, stream>>>(wi0, bi0, wh0, bh0, W0c, b0);
  k_prep_w1<<<4096, 256, 0, stream>>>(wi1, bi1, wh1, bh1, W1c, b1);
  k_embed<<<16384, 256, 0, stream>>>(tokens, casing, pos, emb, x_bf);
  k_init<<<1024, 256, 0, stream>>>(h_init, c_init, h0buf + (size_t)CH * SLOT,
                                   c_st);

  for (int t0 = 0; t0 < 256; t0 += CH) {
    for (int tl = 0; tl < CH; ++tl) {
      int t = t0 + tl;
      // input slot: tl-1; first step reads prev chunk's last slot (CH-1),
      // intact until its tl==CH-1 rewrite -- or h_init slot CH at t=0.
      int in_s = (tl > 0) ? (tl - 1) : ((t0 == 0) ? CH : CH - 1);
      k_step<<<512, 256, 0, stream>>>(
          x_bf + (size_t)t * 81920, W0c, b0,
          h0buf + (size_t)in_s * SLOT,
          h0buf + (size_t)tl * SLOT,
          c0buf + (size_t)tl * SLOT, c_st);
    }
    k_l1gemm<<<64 * CH, 256, 0, stream>>>(h0buf, W1c, b1, c0buf, h1buf);
    k_decode<<<CH * 64, 256, 0, stream>>>(h0buf, h1buf, dec_w, dec_b, out, t0);
  }
}

// Round 14
// 5988.095 us; speedup vs baseline: 1.9233x; 1.0016x over previous
//
#include <hip/hip_runtime.h>
#include <stdint.h>

// ---------------------------------------------------------------------------
// AWD-LSTM eval forward.  T=256, B=256, H=1024, FEAT=319 (=300+7+12), C=13.
// Layer1's recurrent carry is ignored by the reference -> only layer0 is
// sequential; layer1+decoder are parallel over rows.
// Round 14: R13 structure (best: 5998 us).  Budget: layer0 4.47 ms
// (structural: 256 x (4 us work + 13.5 us launch; 6 in-kernel barrier designs
// all >= launch cost)), l1gemm 1.18 ms, decode 0.15, prep 0.2.
// This round: k_l1gemm gets k_step's PROVEN 3-buffer vmcnt(4) staging ring
// (in-block latency hiding stacked on 3-block/CU TLP).  LDS 48 KB (3 bufs x
// 16 KB, epilogue unioned), still 3 blocks/CU (144 <= 160 KB).
// GEMMs: bf16 MFMA 16x16x32, f32 accum; weights gate-interleaved
// (col 4j+p = gate p of unit j) so the LSTM cell fuses into the epilogue.
// ---------------------------------------------------------------------------

typedef __attribute__((ext_vector_type(8))) short bf16x8;
typedef __attribute__((ext_vector_type(4))) float f32x4;

#define SLOT 262144ull  // 256*1024 elements per (B,H) slab

__device__ __forceinline__ uint16_t f2bf(float f) {
  uint32_t u = __float_as_uint(f);
  u += 0x7fffu + ((u >> 16) & 1u);
  return (uint16_t)(u >> 16);
}
__device__ __forceinline__ float bf2f(uint16_t h) {
  return __uint_as_float(((uint32_t)h) << 16);
}
__device__ __forceinline__ float sigmoidf_(float x) {
  return __builtin_amdgcn_rcpf(1.0f + __expf(-x));
}
__device__ __forceinline__ float tanhf_(float x) {
  return 1.0f - 2.0f * __builtin_amdgcn_rcpf(__expf(2.0f * x) + 1.0f);
}
__device__ __forceinline__ void gload_lds16(const void* g, void* l) {
  __builtin_amdgcn_global_load_lds(
      (const __attribute__((address_space(1))) void*)g,
      (__attribute__((address_space(3))) void*)l, 16, 0, 0);
}
// LDS tile: row-major [rows][32 k] bf16; four 16B chunks of each row stored
// permuted: chunk_pos = chunk ^ ((row>>1)&3)  -> ~2-way banks
__device__ __forceinline__ bf16x8 lds_frag(const uint16_t* base, int row, int kc) {
  const uint16_t* p = base + row * 32 + ((kc ^ ((row >> 1) & 3)) << 3);
  return *(const bf16x8*)p;
}
__device__ __forceinline__ f32x4 mfma16(bf16x8 a, bf16x8 b, f32x4 c) {
  return __builtin_amdgcn_mfma_f32_16x16x32_bf16(a, b, c, 0, 0, 0);
}

// ---------------- weight prep ----------------
__global__ __launch_bounds__(256) void k_prep_w0(
    const float* __restrict__ wi0, const float* __restrict__ bi0,
    const float* __restrict__ wh0, const float* __restrict__ bh0,
    uint16_t* __restrict__ W0c, float* __restrict__ b0) {
  int r = blockIdx.x;            // interleaved output row: unit j, gate p
  int p = r & 3, j = r >> 2;
  int src = p * 1024 + j;
  const float* wi = wi0 + (size_t)src * 319;
  const float* wh = wh0 + (size_t)src * 1024;
  uint16_t* dst = W0c + (size_t)r * 1344;
  for (int k = threadIdx.x; k < 1344; k += 256) {
    float v;
    if (k < 319) v = wi[k];
    else if (k == 319) v = 0.0f;
    else v = wh[k - 320];
    dst[k] = f2bf(v);
  }
  if (threadIdx.x == 0) b0[r] = bi0[src] + bh0[src];
}

__global__ __launch_bounds__(256) void k_prep_w1(
    const float* __restrict__ wi1, const float* __restrict__ bi1,
    const float* __restrict__ wh1, const float* __restrict__ bh1,
    uint16_t* __restrict__ W1c, float* __restrict__ b1) {
  int r = blockIdx.x;
  int p = r & 3, j = r >> 2;
  int src = p * 1024 + j;
  const float* wi = wi1 + (size_t)src * 1024;
  const float* wh = wh1 + (size_t)src * 1024;
  uint16_t* dst = W1c + (size_t)r * 2048;
  for (int k = threadIdx.x; k < 2048; k += 256) {
    float v = (k < 1024) ? wi[k] : wh[k - 1024];
    dst[k] = f2bf(v);
  }
  if (threadIdx.x == 0) b1[r] = bi1[src] + bh1[src];
}

__global__ __launch_bounds__(256) void k_init(
    const float* __restrict__ h_init, const float* __restrict__ c_init,
    uint16_t* __restrict__ h_slot, float* __restrict__ c_state) {
  int i = blockIdx.x * 256 + threadIdx.x;  // 262144 = 256*1024
  h_slot[i] = f2bf(h_init[i]);             // layer0 slice of h_init
  c_state[i] = c_init[i];
}

// ---------------- embedding + concat -> x_bf ----------------
__global__ __launch_bounds__(256) void k_embed(
    const int* __restrict__ tokens, const float* __restrict__ casing,
    const float* __restrict__ pos, const float* __restrict__ emb,
    uint16_t* __restrict__ x_bf) {
  int row = blockIdx.x * 4 + (threadIdx.x >> 6);  // (t*256+b)
  int l = threadIdx.x & 63;
  int tok = tokens[row];
  const float* er = emb + (size_t)tok * 300;
  uint16_t* xr = x_bf + (size_t)row * 320;
#pragma unroll
  for (int c0 = 0; c0 < 320; c0 += 64) {
    int c = c0 + l;
    float v;
    if (c < 300) v = er[c];
    else if (c < 307) v = casing[(size_t)row * 7 + (c - 300)];
    else if (c < 319) v = pos[(size_t)row * 12 + (c - 307)];
    else v = 0.0f;
    xr[c] = f2bf(v);
  }
}

// ---------------- layer0 sequential step (R9 verbatim) ----------------
// GEMM [256 x 1344] @ [4096 x 1344]^T, tile 64M x 32N, grid 512 (2 blocks/CU),
// 4 waves 2x2 over (32M,16N).  4-buffer ring, vmcnt(4), one barrier/iter.
__global__ __launch_bounds__(256, 2) void k_step(
    const uint16_t* __restrict__ x_t, const uint16_t* __restrict__ W0c,
    const float* __restrict__ b0, const uint16_t* __restrict__ h_in,
    uint16_t* __restrict__ h_out, uint16_t* __restrict__ c0_out,
    float* __restrict__ c_state) {
  __shared__ __align__(16) uint16_t As[4][2048];  // 64 rows x 32 k
  __shared__ __align__(16) uint16_t Bs[4][1024];  // 32 rows x 32 k
  __shared__ __align__(16) float epi[4][16][20];
  int tid = threadIdx.x;
  int w = tid >> 6, l = tid & 63;
  int wr = w >> 1, wc = w & 1;
  int lid = (blockIdx.x & 7) * 64 + (blockIdx.x >> 3);  // bijective (512=8*64)
  int Mb = (lid & 3) * 64;    // batch tile (64 rows)
  int Nb = (lid >> 2) * 32;   // output-col tile (32 interleaved cols)
  f32x4 acc[2] = {};

  int sc = (l & 3) ^ ((l >> 3) & 3);  // global chunk for this lane's LDS slot
  const uint16_t* xrow = x_t + (size_t)(Mb + w * 16 + (l >> 2)) * 320 + sc * 8;
  const uint16_t* hrow = h_in + (size_t)(Mb + w * 16 + (l >> 2)) * 1024 + sc * 8;
  const uint16_t* wrow =
      W0c + (size_t)(Nb + (w & 1) * 16 + (l >> 2)) * 1344 + sc * 8;

  auto stage = [&](int kt, int buf) {
    int kg = kt * 32;
    const uint16_t* sA = (kt < 10) ? (xrow + kg) : (hrow + (kg - 320));
    gload_lds16(sA, &As[buf][w * 512]);
    gload_lds16(wrow + kg, &Bs[buf][(w & 1) * 512]);
  };

  stage(0, 0);
  stage(1, 1);
  stage(2, 2);
  for (int kt = 0; kt < 42; ++kt) {
    __builtin_amdgcn_sched_barrier(0);
    if (kt < 40) asm volatile("s_waitcnt vmcnt(4)" ::: "memory");
    else if (kt == 40) asm volatile("s_waitcnt vmcnt(2)" ::: "memory");
    else asm volatile("s_waitcnt vmcnt(0)" ::: "memory");
    __builtin_amdgcn_s_barrier();
    __builtin_amdgcn_sched_barrier(0);
    if (kt < 39) stage(kt + 3, (kt + 3) & 3);
    const uint16_t* Ab = As[kt & 3];
    const uint16_t* Bb = Bs[kt & 3];
    bf16x8 a0 = lds_frag(Ab, wr * 32 + (l & 15), l >> 4);
    bf16x8 a1 = lds_frag(Ab, wr * 32 + 16 + (l & 15), l >> 4);
    bf16x8 q0 = lds_frag(Bb, wc * 16 + (l & 15), l >> 4);
    acc[0] = mfma16(a0, q0, acc[0]);
    acc[1] = mfma16(a1, q0, acc[1]);
  }

  // fused LSTM cell epilogue: per wave 32x16 outputs = 2 frags, 2 cells/thread
  int jbase = (Nb + wc * 16) >> 2;
#pragma unroll
  for (int m = 0; m < 2; ++m) {
#pragma unroll
    for (int r = 0; r < 4; ++r)
      epi[w][(l >> 4) * 4 + r][l & 15] = acc[m][r];
    asm volatile("s_waitcnt lgkmcnt(0)" ::: "memory");
    {
      int rr = l >> 2, j = l & 3;
      f32x4 q = *(const f32x4*)&epi[w][rr][j * 4];
      f32x4 bv = *(const f32x4*)&b0[(jbase + j) * 4];
      float vi = sigmoidf_(q[0] + bv[0]);
      float vf = sigmoidf_(q[1] + bv[1]);
      float vo = sigmoidf_(q[2] + bv[2]);
      float vg = tanhf_(q[3] + bv[3]);
      int bg = Mb + wr * 32 + m * 16 + rr;
      int jg = jbase + j;
      size_t sidx = (size_t)bg * 1024 + jg;
      float cold = c_state[sidx];
      float cn = vf * cold + vi * vg;
      float hh = vo * tanhf_(cn);
      c_state[sidx] = cn;
      c0_out[sidx] = f2bf(cn);
      h_out[sidx] = f2bf(hh);
    }
    asm volatile("s_waitcnt lgkmcnt(0)" ::: "memory");
  }
}

// ---------------- layer1 GEMM over one chunk ----------------
// rows = CH*256; A row (t,b) = [h0(t,b) | h0(t,255-b)]  (slot tl of h0buf).
// tile 128x128, 4 waves (2x2) x (4x4 frags), fused cell epilogue.
// 1-D grid 64*CH, XCD-chunked swizzle: XCD k owns N-panels [4k,4k+4).
// NEW: 3-buffer vmcnt(4) staging ring (k_step's proven pattern) -- stage
// tile kt+2 while computing kt; one barrier per iter; LDS 48 KB (3 bufs x
// 16 KB, epilogue unioned) -> still 3 blocks/CU (144 <= 160 KB).
__global__ __launch_bounds__(256, 3) void k_l1gemm(
    const uint16_t* __restrict__ h0buf, const uint16_t* __restrict__ W1c,
    const float* __restrict__ b1, const uint16_t* __restrict__ c0buf,
    uint16_t* __restrict__ h1buf) {
  __shared__ __align__(16) char smem[49152];  // 3 x (As 8192 + Bs 8192)
  float* epif = (float*)smem;                 // [4][16][68] f32 = 17408 B
  int tid = threadIdx.x;
  int w = tid >> 6, l = tid & 63;
  int wr = w >> 1, wc = w & 1;
  uint32_t G = gridDim.x;          // 64*CH (divisible by 8)
  uint32_t cpx = G >> 3;
  uint32_t lid = (blockIdx.x & 7) * cpx + (blockIdx.x >> 3);  // bijective
  uint32_t yyTot = G >> 5;         // 2*CH row-tiles per N-panel
  uint32_t nb = lid / yyTot;       // N-panel 0..31
  uint32_t yy = lid - nb * yyTot;  // row tile 0..2CH-1
  int Nb = (int)nb * 128;
  int tl = (int)(yy >> 1);
  int bbase = (int)(yy & 1) * 128;
  const uint16_t* hrow = h0buf + (size_t)tl * SLOT;
  const uint16_t* c0s = c0buf + (size_t)tl * SLOT;
  uint16_t* h1s = h1buf + (size_t)tl * SLOT;
  f32x4 acc[4][4] = {};

  int sc = (l & 3) ^ ((l >> 3) & 3);
  int srow0 = (w * 2 + 0) * 16 + (l >> 2);
  int srow1 = (w * 2 + 1) * 16 + (l >> 2);
  const uint16_t* hA0n = hrow + (size_t)(bbase + srow0) * 1024;
  const uint16_t* hA0f = hrow + (size_t)(255 - (bbase + srow0)) * 1024;
  const uint16_t* hA1n = hrow + (size_t)(bbase + srow1) * 1024;
  const uint16_t* hA1f = hrow + (size_t)(255 - (bbase + srow1)) * 1024;
  const uint16_t* wB0 = W1c + (size_t)(Nb + srow0) * 2048;
  const uint16_t* wB1 = W1c + (size_t)(Nb + srow1) * 2048;

  auto stage = [&](int kt, int buf) {
    int kg = kt * 32 + sc * 8;
    const uint16_t* sA0 = (kg < 1024) ? (hA0n + kg) : (hA0f + (kg - 1024));
    const uint16_t* sA1 = (kg < 1024) ? (hA1n + kg) : (hA1f + (kg - 1024));
    char* base = smem + buf * 16384;
    gload_lds16(sA0, base + (w * 2 + 0) * 1024);
    gload_lds16(sA1, base + (w * 2 + 1) * 1024);
    gload_lds16(wB0 + kg, base + 8192 + (w * 2 + 0) * 1024);
    gload_lds16(wB1 + kg, base + 8192 + (w * 2 + 1) * 1024);
  };

  stage(0, 0);
  stage(1, 1);
  for (int kt = 0; kt < 64; ++kt) {
    __builtin_amdgcn_sched_barrier(0);
    if (kt < 63) asm volatile("s_waitcnt vmcnt(4)" ::: "memory");
    else asm volatile("s_waitcnt vmcnt(0)" ::: "memory");
    __builtin_amdgcn_s_barrier();
    __builtin_amdgcn_sched_barrier(0);
    if (kt < 62) stage(kt + 2, (kt + 2) % 3);
    const uint16_t* As = (const uint16_t*)(smem + (kt % 3) * 16384);
    const uint16_t* Bs = As + 4096;
    bf16x8 a[4], q[4];
#pragma unroll
    for (int m = 0; m < 4; ++m) a[m] = lds_frag(As, wr * 64 + m * 16 + (l & 15), l >> 4);
#pragma unroll
    for (int n = 0; n < 4; ++n) q[n] = lds_frag(Bs, wc * 64 + n * 16 + (l & 15), l >> 4);
#pragma unroll
    for (int m = 0; m < 4; ++m)
#pragma unroll
      for (int n = 0; n < 4; ++n) acc[m][n] = mfma16(a[m], q[n], acc[m][n]);
  }
  __syncthreads();  // all reads of smem tiles done -> safe to reuse as epi

  int jbase = (Nb + wc * 64) >> 2;
#pragma unroll
  for (int m = 0; m < 4; ++m) {
#pragma unroll
    for (int n = 0; n < 4; ++n)
#pragma unroll
      for (int r = 0; r < 4; ++r)
        epif[((size_t)w * 16 + (l >> 4) * 4 + r) * 68 + n * 16 + (l & 15)] =
            acc[m][n][r];
    asm volatile("s_waitcnt lgkmcnt(0)" ::: "memory");
#pragma unroll
    for (int it = 0; it < 4; ++it) {
      int pp = it * 64 + l;
      int rr = pp >> 4, j = pp & 15;
      f32x4 q = *(const f32x4*)&epif[((size_t)w * 16 + rr) * 68 + j * 4];
      f32x4 bv = *(const f32x4*)&b1[(size_t)(jbase + j) * 4];
      float vi = sigmoidf_(q[0] + bv[0]);
      float vf = sigmoidf_(q[1] + bv[1]);
      float vo = sigmoidf_(q[2] + bv[2]);
      float vg = tanhf_(q[3] + bv[3]);
      int rowl = wr * 64 + m * 16 + rr;
      int b = bbase + rowl;
      int jg = jbase + j;
      float c0v = bf2f(c0s[(size_t)(255 - b) * 1024 + jg]);
      float cn = vf * c0v + vi * vg;
      float hh = vo * tanhf_(cn);
      h1s[(size_t)b * 1024 + jg] = f2bf(hh);
    }
    asm volatile("s_waitcnt lgkmcnt(0)" ::: "memory");
  }
}

// ---------------- decoder over one chunk ----------------
__global__ __launch_bounds__(256) void k_decode(
    const uint16_t* __restrict__ h0buf, const uint16_t* __restrict__ h1buf,
    const float* __restrict__ dec_w, const float* __restrict__ dec_b,
    float* __restrict__ out, int t0) {
  int rowl = blockIdx.x * 4 + (threadIdx.x >> 6);  // chunk-local row
  int l = threadIdx.x & 63;
  int tl = rowl >> 8, b = rowl & 255;
  const uint16_t* h0 = h0buf + (size_t)tl * SLOT + (size_t)b * 1024;
  const uint16_t* h1 = h1buf + (size_t)tl * SLOT + (size_t)b * 1024;
  float acc[13];
#pragma unroll
  for (int c = 0; c < 13; ++c) acc[c] = 0.0f;
#pragma unroll
  for (int part = 0; part < 2; ++part) {
    const uint16_t* h = part ? h1 : h0;
    const float* wb = dec_w + part * 1024 + (size_t)l * 16;
    float hv[16];
    const bf16x8* hp = (const bf16x8*)(h + l * 16);
    bf16x8 v0 = hp[0];
    bf16x8 v1 = hp[1];
#pragma unroll
    for (int jj = 0; jj < 8; ++jj) {
      hv[jj] = bf2f((uint16_t)v0[jj]);
      hv[8 + jj] = bf2f((uint16_t)v1[jj]);
    }
#pragma unroll
    for (int c = 0; c < 13; ++c) {
      const float* wc = wb + (size_t)c * 2048;
      float s = 0.0f;
#pragma unroll
      for (int jj = 0; jj < 16; ++jj) s += hv[jj] * wc[jj];
      acc[c] += s;
    }
  }
#pragma unroll
  for (int c = 0; c < 13; ++c) {
    float v = acc[c];
#pragma unroll
    for (int off = 32; off > 0; off >>= 1) v += __shfl_xor(v, off, 64);
    acc[c] = v;
  }
  if (l == 0) {
    int t = t0 + tl;
    float* orow = out + ((size_t)t * 256 + b) * 13;
#pragma unroll
    for (int c = 0; c < 13; ++c) orow[c] = acc[c] + dec_b[c];
  }
}

// ---------------- host ----------------
extern "C" void kernel_launch(void* const* d_in, const int* in_sizes, int n_in,
                              void* d_out, int out_size, void* d_ws, size_t ws_size,
                              hipStream_t stream) {
  const int* tokens = (const int*)d_in[0];
  const float* casing = (const float*)d_in[1];
  const float* pos = (const float*)d_in[2];
  const float* emb = (const float*)d_in[3];
  const float* wi0 = (const float*)d_in[4];
  const float* bi0 = (const float*)d_in[5];
  const float* wh0 = (const float*)d_in[6];
  const float* bh0 = (const float*)d_in[7];
  const float* wi1 = (const float*)d_in[8];
  const float* bi1 = (const float*)d_in[9];
  const float* wh1 = (const float*)d_in[10];
  const float* bh1 = (const float*)d_in[11];
  const float* dec_w = (const float*)d_in[12];
  const float* dec_b = (const float*)d_in[13];
  const float* h_init = (const float*)d_in[14];
  const float* c_init = (const float*)d_in[15];
  float* out = (float*)d_out;
  (void)in_sizes; (void)n_in; (void)out_size;

  char* ws = (char*)d_ws;
  size_t off = 0;
  auto alloc = [&](size_t bytes) {
    char* p = ws + off;
    off += (bytes + 255) & ~(size_t)255;
    return p;
  };
  // fixed buffers (~69 MB)
  uint16_t* W0c = (uint16_t*)alloc(4096ull * 1344 * 2);
  float* b0 = (float*)alloc(4096 * 4);
  uint16_t* W1c = (uint16_t*)alloc(4096ull * 2048 * 2);
  float* b1 = (float*)alloc(4096 * 4);
  uint16_t* x_bf = (uint16_t*)alloc(65536ull * 320 * 2);
  float* c_st = (float*)alloc(SLOT * 4);

  // chunk size: (CH+1) + CH + CH slots of SLOT*2 bytes
  const size_t SB = SLOT * 2;  // 524288, 256-aligned
  int CH = 0;
  for (int c = 64; c >= 2; c >>= 1) {
    if (off + (size_t)(3 * c + 1) * SB + 4096 <= ws_size) { CH = c; break; }
  }
  if (CH == 0) return;  // ws too small (diagnostic: poisoned output)
  uint16_t* h0buf = (uint16_t*)alloc((size_t)(CH + 1) * SB);  // slot CH = h_init
  uint16_t* c0buf = (uint16_t*)alloc((size_t)CH * SB);
  uint16_t* h1buf = (uint16_t*)alloc((size_t)CH * SB);

  k_prep_w0<<<4096, 256, 0, stream>>>(wi0, bi0, wh0, bh0, W0c, b0);
  k_prep_w1<<<4096, 256, 0, stream>>>(wi1, bi1, wh1, bh1, W1c, b1);
  k_embed<<<16384, 256, 0, stream>>>(tokens, casing, pos, emb, x_bf);
  k_init<<<1024, 256, 0, stream>>>(h_init, c_init, h0buf + (size_t)CH * SLOT,
                                   c_st);

  for (int t0 = 0; t0 < 256; t0 += CH) {
    for (int tl = 0; tl < CH; ++tl) {
      int t = t0 + tl;
      // input slot: tl-1; first step reads prev chunk's last slot (CH-1),
      // intact until its tl==CH-1 rewrite -- or h_init slot CH at t=0.
      int in_s = (tl > 0) ? (tl - 1) : ((t0 == 0) ? CH : CH - 1);
      k_step<<<512, 256, 0, stream>>>(
          x_bf + (size_t)t * 81920, W0c, b0,
          h0buf + (size_t)in_s * SLOT,
          h0buf + (size_t)tl * SLOT,
          c0buf + (size_t)tl * SLOT, c_st);
    }
    k_l1gemm<<<64 * CH, 256, 0, stream>>>(h0buf, W1c, b1, c0buf, h1buf);
    k_decode<<<CH * 64, 256, 0, stream>>>(h0buf, h1buf, dec_w, dec_b, out, t0);
  }
}

// Round 15
// 4690.704 us; speedup vs baseline: 2.4553x; 1.2766x over previous
//
#include <hip/hip_runtime.h>
#include <stdint.h>

// ---------------------------------------------------------------------------
// AWD-LSTM eval forward.  T=256, B=256, H=1024, FEAT=319 (=300+7+12), C=13.
// Layer1's recurrent carry is ignored by the reference -> only layer0 is
// sequential; layer1+decoder are parallel over rows.
// Round 15: layer0 step at 4 blocks/CU.  Occupancy ladder: 1/CU=18.7us,
// 2/CU=17.4us per step (launch gap ~13.5us is fixed; work is latency-bound).
// k_step re-tiled 32Mx32N, grid 1024; 4 waves 2x2 over (16M,16N); waves 0/1
// stage A halves, 2/3 stage B halves (1KB/wave/iter, balanced); 4-buffer
// ring with vmcnt(2/1/0); epilogue 1 LSTM cell/thread.  l1gemm/decode/prep
// = R14 verbatim (l1 at the 2-barrier structure's ~930 TF ceiling).
// GEMMs: bf16 MFMA 16x16x32, f32 accum; weights gate-interleaved
// (col 4j+p = gate p of unit j) so the LSTM cell fuses into the epilogue.
// ---------------------------------------------------------------------------

typedef __attribute__((ext_vector_type(8))) short bf16x8;
typedef __attribute__((ext_vector_type(4))) float f32x4;

#define SLOT 262144ull  // 256*1024 elements per (B,H) slab

__device__ __forceinline__ uint16_t f2bf(float f) {
  uint32_t u = __float_as_uint(f);
  u += 0x7fffu + ((u >> 16) & 1u);
  return (uint16_t)(u >> 16);
}
__device__ __forceinline__ float bf2f(uint16_t h) {
  return __uint_as_float(((uint32_t)h) << 16);
}
__device__ __forceinline__ float sigmoidf_(float x) {
  return __builtin_amdgcn_rcpf(1.0f + __expf(-x));
}
__device__ __forceinline__ float tanhf_(float x) {
  return 1.0f - 2.0f * __builtin_amdgcn_rcpf(__expf(2.0f * x) + 1.0f);
}
__device__ __forceinline__ void gload_lds16(const void* g, void* l) {
  __builtin_amdgcn_global_load_lds(
      (const __attribute__((address_space(1))) void*)g,
      (__attribute__((address_space(3))) void*)l, 16, 0, 0);
}
// LDS tile: row-major [rows][32 k] bf16; four 16B chunks of each row stored
// permuted: chunk_pos = chunk ^ ((row>>1)&3)  -> ~2-way banks
__device__ __forceinline__ bf16x8 lds_frag(const uint16_t* base, int row, int kc) {
  const uint16_t* p = base + row * 32 + ((kc ^ ((row >> 1) & 3)) << 3);
  return *(const bf16x8*)p;
}
__device__ __forceinline__ f32x4 mfma16(bf16x8 a, bf16x8 b, f32x4 c) {
  return __builtin_amdgcn_mfma_f32_16x16x32_bf16(a, b, c, 0, 0, 0);
}

// ---------------- weight prep ----------------
__global__ __launch_bounds__(256) void k_prep_w0(
    const float* __restrict__ wi0, const float* __restrict__ bi0,
    const float* __restrict__ wh0, const float* __restrict__ bh0,
    uint16_t* __restrict__ W0c, float* __restrict__ b0) {
  int r = blockIdx.x;            // interleaved output row: unit j, gate p
  int p = r & 3, j = r >> 2;
  int src = p * 1024 + j;
  const float* wi = wi0 + (size_t)src * 319;
  const float* wh = wh0 + (size_t)src * 1024;
  uint16_t* dst = W0c + (size_t)r * 1344;
  for (int k = threadIdx.x; k < 1344; k += 256) {
    float v;
    if (k < 319) v = wi[k];
    else if (k == 319) v = 0.0f;
    else v = wh[k - 320];
    dst[k] = f2bf(v);
  }
  if (threadIdx.x == 0) b0[r] = bi0[src] + bh0[src];
}

__global__ __launch_bounds__(256) void k_prep_w1(
    const float* __restrict__ wi1, const float* __restrict__ bi1,
    const float* __restrict__ wh1, const float* __restrict__ bh1,
    uint16_t* __restrict__ W1c, float* __restrict__ b1) {
  int r = blockIdx.x;
  int p = r & 3, j = r >> 2;
  int src = p * 1024 + j;
  const float* wi = wi1 + (size_t)src * 1024;
  const float* wh = wh1 + (size_t)src * 1024;
  uint16_t* dst = W1c + (size_t)r * 2048;
  for (int k = threadIdx.x; k < 2048; k += 256) {
    float v = (k < 1024) ? wi[k] : wh[k - 1024];
    dst[k] = f2bf(v);
  }
  if (threadIdx.x == 0) b1[r] = bi1[src] + bh1[src];
}

__global__ __launch_bounds__(256) void k_init(
    const float* __restrict__ h_init, const float* __restrict__ c_init,
    uint16_t* __restrict__ h_slot, float* __restrict__ c_state) {
  int i = blockIdx.x * 256 + threadIdx.x;  // 262144 = 256*1024
  h_slot[i] = f2bf(h_init[i]);             // layer0 slice of h_init
  c_state[i] = c_init[i];
}

// ---------------- embedding + concat -> x_bf ----------------
__global__ __launch_bounds__(256) void k_embed(
    const int* __restrict__ tokens, const float* __restrict__ casing,
    const float* __restrict__ pos, const float* __restrict__ emb,
    uint16_t* __restrict__ x_bf) {
  int row = blockIdx.x * 4 + (threadIdx.x >> 6);  // (t*256+b)
  int l = threadIdx.x & 63;
  int tok = tokens[row];
  const float* er = emb + (size_t)tok * 300;
  uint16_t* xr = x_bf + (size_t)row * 320;
#pragma unroll
  for (int c0 = 0; c0 < 320; c0 += 64) {
    int c = c0 + l;
    float v;
    if (c < 300) v = er[c];
    else if (c < 307) v = casing[(size_t)row * 7 + (c - 300)];
    else if (c < 319) v = pos[(size_t)row * 12 + (c - 307)];
    else v = 0.0f;
    xr[c] = f2bf(v);
  }
}

// ---------------- layer0 sequential step ----------------
// GEMM [256 x 1344] @ [4096 x 1344]^T, tile 32M x 32N, grid 1024
// (4 blocks/CU), 4 waves 2x2 over (16M,16N).  Waves 0/1 stage A halves,
// waves 2/3 stage B halves (1 KB each/iter).  4-buffer ring, vmcnt(2/1/0),
// one barrier/iter.  Fused LSTM cell: 1 cell/thread.
// XCD-chunked swizzle: XCD k owns col-tiles [16k,16k+16) (1.4 MB W, L2-res).
__global__ __launch_bounds__(256, 4) void k_step(
    const uint16_t* __restrict__ x_t, const uint16_t* __restrict__ W0c,
    const float* __restrict__ b0, const uint16_t* __restrict__ h_in,
    uint16_t* __restrict__ h_out, uint16_t* __restrict__ c0_out,
    float* __restrict__ c_state) {
  __shared__ __align__(16) uint16_t As[4][1024];  // 32 rows x 32 k
  __shared__ __align__(16) uint16_t Bs[4][1024];  // 32 rows x 32 k
  __shared__ __align__(16) float epi[4][16][20];
  int tid = threadIdx.x;
  int w = tid >> 6, l = tid & 63;
  int wr = w >> 1, wc = w & 1;
  int lid = (blockIdx.x & 7) * 128 + (blockIdx.x >> 3);  // bijective 1024=8*128
  int Mb = (lid & 7) * 32;    // batch tile (32 rows)
  int Nb = (lid >> 3) * 32;   // output-col tile (32 interleaved cols)
  f32x4 acc = {};

  // staging roles: w=0/1 -> A half w (16 rows); w=2/3 -> B half w&1.
  // lane -> row l>>2 within half, LDS chunk slot l&3, global chunk sc.
  int sc = (l & 3) ^ ((l >> 3) & 3);
  const uint16_t* xrow =
      x_t + (size_t)(Mb + (w & 1) * 16 + (l >> 2)) * 320 + sc * 8;
  const uint16_t* hrow =
      h_in + (size_t)(Mb + (w & 1) * 16 + (l >> 2)) * 1024 + sc * 8;
  const uint16_t* wrow =
      W0c + (size_t)(Nb + (w & 1) * 16 + (l >> 2)) * 1344 + sc * 8;

  auto stage = [&](int kt, int buf) {
    int kg = kt * 32;
    if (w < 2) {
      const uint16_t* sA = (kt < 10) ? (xrow + kg) : (hrow + (kg - 320));
      gload_lds16(sA, &As[buf][w * 512]);
    } else {
      gload_lds16(wrow + kg, &Bs[buf][(w & 1) * 512]);
    }
  };

  stage(0, 0);
  stage(1, 1);
  stage(2, 2);
  for (int kt = 0; kt < 42; ++kt) {
    __builtin_amdgcn_sched_barrier(0);
    if (kt < 40) asm volatile("s_waitcnt vmcnt(2)" ::: "memory");
    else if (kt == 40) asm volatile("s_waitcnt vmcnt(1)" ::: "memory");
    else asm volatile("s_waitcnt vmcnt(0)" ::: "memory");
    __builtin_amdgcn_s_barrier();
    __builtin_amdgcn_sched_barrier(0);
    if (kt < 39) stage(kt + 3, (kt + 3) & 3);
    const uint16_t* Ab = As[kt & 3];
    const uint16_t* Bb = Bs[kt & 3];
    bf16x8 a0 = lds_frag(Ab, wr * 16 + (l & 15), l >> 4);
    bf16x8 q0 = lds_frag(Bb, wc * 16 + (l & 15), l >> 4);
    acc = mfma16(a0, q0, acc);
  }

  // fused LSTM cell epilogue: wave covers 16 rows x 16 cols; after the epi
  // redistribution each lane owns ONE cell (row rr, unit jbase+j: 4 gates
  // are 4 consecutive interleaved cols).
  int jbase = (Nb + wc * 16) >> 2;
#pragma unroll
  for (int r = 0; r < 4; ++r)
    epi[w][(l >> 4) * 4 + r][l & 15] = acc[r];
  asm volatile("s_waitcnt lgkmcnt(0)" ::: "memory");
  {
    int rr = l >> 2, j = l & 3;
    f32x4 q = *(const f32x4*)&epi[w][rr][j * 4];
    f32x4 bv = *(const f32x4*)&b0[(jbase + j) * 4];
    float vi = sigmoidf_(q[0] + bv[0]);
    float vf = sigmoidf_(q[1] + bv[1]);
    float vo = sigmoidf_(q[2] + bv[2]);
    float vg = tanhf_(q[3] + bv[3]);
    int bg = Mb + wr * 16 + rr;
    int jg = jbase + j;
    size_t sidx = (size_t)bg * 1024 + jg;
    float cold = c_state[sidx];
    float cn = vf * cold + vi * vg;
    float hh = vo * tanhf_(cn);
    c_state[sidx] = cn;
    c0_out[sidx] = f2bf(cn);
    h_out[sidx] = f2bf(hh);
  }
}

// ---------------- layer1 GEMM over one chunk (R14 verbatim) ----------------
// rows = CH*256; A row (t,b) = [h0(t,b) | h0(t,255-b)]  (slot tl of h0buf).
// tile 128x128, 4 waves (2x2) x (4x4 frags), fused cell epilogue.
// 1-D grid 64*CH, XCD-chunked swizzle; 3-buffer vmcnt(4) ring; LDS 48 KB
// (epilogue unioned) -> 3 blocks/CU.
__global__ __launch_bounds__(256, 3) void k_l1gemm(
    const uint16_t* __restrict__ h0buf, const uint16_t* __restrict__ W1c,
    const float* __restrict__ b1, const uint16_t* __restrict__ c0buf,
    uint16_t* __restrict__ h1buf) {
  __shared__ __align__(16) char smem[49152];  // 3 x (As 8192 + Bs 8192)
  float* epif = (float*)smem;                 // [4][16][68] f32 = 17408 B
  int tid = threadIdx.x;
  int w = tid >> 6, l = tid & 63;
  int wr = w >> 1, wc = w & 1;
  uint32_t G = gridDim.x;          // 64*CH (divisible by 8)
  uint32_t cpx = G >> 3;
  uint32_t lid = (blockIdx.x & 7) * cpx + (blockIdx.x >> 3);  // bijective
  uint32_t yyTot = G >> 5;         // 2*CH row-tiles per N-panel
  uint32_t nb = lid / yyTot;       // N-panel 0..31
  uint32_t yy = lid - nb * yyTot;  // row tile 0..2CH-1
  int Nb = (int)nb * 128;
  int tl = (int)(yy >> 1);
  int bbase = (int)(yy & 1) * 128;
  const uint16_t* hrow = h0buf + (size_t)tl * SLOT;
  const uint16_t* c0s = c0buf + (size_t)tl * SLOT;
  uint16_t* h1s = h1buf + (size_t)tl * SLOT;
  f32x4 acc[4][4] = {};

  int sc = (l & 3) ^ ((l >> 3) & 3);
  int srow0 = (w * 2 + 0) * 16 + (l >> 2);
  int srow1 = (w * 2 + 1) * 16 + (l >> 2);
  const uint16_t* hA0n = hrow + (size_t)(bbase + srow0) * 1024;
  const uint16_t* hA0f = hrow + (size_t)(255 - (bbase + srow0)) * 1024;
  const uint16_t* hA1n = hrow + (size_t)(bbase + srow1) * 1024;
  const uint16_t* hA1f = hrow + (size_t)(255 - (bbase + srow1)) * 1024;
  const uint16_t* wB0 = W1c + (size_t)(Nb + srow0) * 2048;
  const uint16_t* wB1 = W1c + (size_t)(Nb + srow1) * 2048;

  auto stage = [&](int kt, int buf) {
    int kg = kt * 32 + sc * 8;
    const uint16_t* sA0 = (kg < 1024) ? (hA0n + kg) : (hA0f + (kg - 1024));
    const uint16_t* sA1 = (kg < 1024) ? (hA1n + kg) : (hA1f + (kg - 1024));
    char* base = smem + buf * 16384;
    gload_lds16(sA0, base + (w * 2 + 0) * 1024);
    gload_lds16(sA1, base + (w * 2 + 1) * 1024);
    gload_lds16(wB0 + kg, base + 8192 + (w * 2 + 0) * 1024);
    gload_lds16(wB1 + kg, base + 8192 + (w * 2 + 1) * 1024);
  };

  stage(0, 0);
  stage(1, 1);
  for (int kt = 0; kt < 64; ++kt) {
    __builtin_amdgcn_sched_barrier(0);
    if (kt < 63) asm volatile("s_waitcnt vmcnt(4)" ::: "memory");
    else asm volatile("s_waitcnt vmcnt(0)" ::: "memory");
    __builtin_amdgcn_s_barrier();
    __builtin_amdgcn_sched_barrier(0);
    if (kt < 62) stage(kt + 2, (kt + 2) % 3);
    const uint16_t* As = (const uint16_t*)(smem + (kt % 3) * 16384);
    const uint16_t* Bs = As + 4096;
    bf16x8 a[4], q[4];
#pragma unroll
    for (int m = 0; m < 4; ++m) a[m] = lds_frag(As, wr * 64 + m * 16 + (l & 15), l >> 4);
#pragma unroll
    for (int n = 0; n < 4; ++n) q[n] = lds_frag(Bs, wc * 64 + n * 16 + (l & 15), l >> 4);
#pragma unroll
    for (int m = 0; m < 4; ++m)
#pragma unroll
      for (int n = 0; n < 4; ++n) acc[m][n] = mfma16(a[m], q[n], acc[m][n]);
  }
  __syncthreads();  // all reads of smem tiles done -> safe to reuse as epi

  int jbase = (Nb + wc * 64) >> 2;
#pragma unroll
  for (int m = 0; m < 4; ++m) {
#pragma unroll
    for (int n = 0; n < 4; ++n)
#pragma unroll
      for (int r = 0; r < 4; ++r)
        epif[((size_t)w * 16 + (l >> 4) * 4 + r) * 68 + n * 16 + (l & 15)] =
            acc[m][n][r];
    asm volatile("s_waitcnt lgkmcnt(0)" ::: "memory");
#pragma unroll
    for (int it = 0; it < 4; ++it) {
      int pp = it * 64 + l;
      int rr = pp >> 4, j = pp & 15;
      f32x4 q = *(const f32x4*)&epif[((size_t)w * 16 + rr) * 68 + j * 4];
      f32x4 bv = *(const f32x4*)&b1[(size_t)(jbase + j) * 4];
      float vi = sigmoidf_(q[0] + bv[0]);
      float vf = sigmoidf_(q[1] + bv[1]);
      float vo = sigmoidf_(q[2] + bv[2]);
      float vg = tanhf_(q[3] + bv[3]);
      int rowl = wr * 64 + m * 16 + rr;
      int b = bbase + rowl;
      int jg = jbase + j;
      float c0v = bf2f(c0s[(size_t)(255 - b) * 1024 + jg]);
      float cn = vf * c0v + vi * vg;
      float hh = vo * tanhf_(cn);
      h1s[(size_t)b * 1024 + jg] = f2bf(hh);
    }
    asm volatile("s_waitcnt lgkmcnt(0)" ::: "memory");
  }
}

// ---------------- decoder over one chunk ----------------
__global__ __launch_bounds__(256) void k_decode(
    const uint16_t* __restrict__ h0buf, const uint16_t* __restrict__ h1buf,
    const float* __restrict__ dec_w, const float* __restrict__ dec_b,
    float* __restrict__ out, int t0) {
  int rowl = blockIdx.x * 4 + (threadIdx.x >> 6);  // chunk-local row
  int l = threadIdx.x & 63;
  int tl = rowl >> 8, b = rowl & 255;
  const uint16_t* h0 = h0buf + (size_t)tl * SLOT + (size_t)b * 1024;
  const uint16_t* h1 = h1buf + (size_t)tl * SLOT + (size_t)b * 1024;
  float acc[13];
#pragma unroll
  for (int c = 0; c < 13; ++c) acc[c] = 0.0f;
#pragma unroll
  for (int part = 0; part < 2; ++part) {
    const uint16_t* h = part ? h1 : h0;
    const float* wb = dec_w + part * 1024 + (size_t)l * 16;
    float hv[16];
    const bf16x8* hp = (const bf16x8*)(h + l * 16);
    bf16x8 v0 = hp[0];
    bf16x8 v1 = hp[1];
#pragma unroll
    for (int jj = 0; jj < 8; ++jj) {
      hv[jj] = bf2f((uint16_t)v0[jj]);
      hv[8 + jj] = bf2f((uint16_t)v1[jj]);
    }
#pragma unroll
    for (int c = 0; c < 13; ++c) {
      const float* wc = wb + (size_t)c * 2048;
      float s = 0.0f;
#pragma unroll
      for (int jj = 0; jj < 16; ++jj) s += hv[jj] * wc[jj];
      acc[c] += s;
    }
  }
#pragma unroll
  for (int c = 0; c < 13; ++c) {
    float v = acc[c];
#pragma unroll
    for (int off = 32; off > 0; off >>= 1) v += __shfl_xor(v, off, 64);
    acc[c] = v;
  }
  if (l == 0) {
    int t = t0 + tl;
    float* orow = out + ((size_t)t * 256 + b) * 13;
#pragma unroll
    for (int c = 0; c < 13; ++c) orow[c] = acc[c] + dec_b[c];
  }
}

// ---------------- host ----------------
extern "C" void kernel_launch(void* const* d_in, const int* in_sizes, int n_in,
                              void* d_out, int out_size, void* d_ws, size_t ws_size,
                              hipStream_t stream) {
  const int* tokens = (const int*)d_in[0];
  const float* casing = (const float*)d_in[1];
  const float* pos = (const float*)d_in[2];
  const float* emb = (const float*)d_in[3];
  const float* wi0 = (const float*)d_in[4];
  const float* bi0 = (const float*)d_in[5];
  const float* wh0 = (const float*)d_in[6];
  const float* bh0 = (const float*)d_in[7];
  const float* wi1 = (const float*)d_in[8];
  const float* bi1 = (const float*)d_in[9];
  const float* wh1 = (const float*)d_in[10];
  const float* bh1 = (const float*)d_in[11];
  const float* dec_w = (const float*)d_in[12];
  const float* dec_b = (const float*)d_in[13];
  const float* h_init = (const float*)d_in[14];
  const float* c_init = (const float*)d_in[15];
  float* out = (float*)d_out;
  (void)in_sizes; (void)n_in; (void)out_size;

  char* ws = (char*)d_ws;
  size_t off = 0;
  auto alloc = [&](size_t bytes) {
    char* p = ws + off;
    off += (bytes + 255) & ~(size_t)255;
    return p;
  };
  // fixed buffers (~69 MB)
  uint16_t* W0c = (uint16_t*)alloc(4096ull * 1344 * 2);
  float* b0 = (float*)alloc(4096 * 4);
  uint16_t* W1c = (uint16_t*)alloc(4096ull * 2048 * 2);
  float* b1 = (float*)alloc(4096 * 4);
  uint16_t* x_bf = (uint16_t*)alloc(65536ull * 320 * 2);
  float* c_st = (float*)alloc(SLOT * 4);

  // chunk size: (CH+1) + CH + CH slots of SLOT*2 bytes
  const size_t SB = SLOT * 2;  // 524288, 256-aligned
  int CH = 0;
  for (int c = 64; c >= 2; c >>= 1) {
    if (off + (size_t)(3 * c + 1) * SB + 4096 <= ws_size) { CH = c; break; }
  }
  if (CH == 0) return;  // ws too small (diagnostic: poisoned output)
  uint16_t* h0buf = (uint16_t*)alloc((size_t)(CH + 1) * SB);  // slot CH = h_init
  uint16_t* c0buf = (uint16_t*)alloc((size_t)CH * SB);
  uint16_t* h1buf = (uint16_t*)alloc((size_t)CH * SB);

  k_prep_w0<<<4096, 256, 0, stream>>>(wi0, bi0, wh0, bh0, W0c, b0);
  k_prep_w1<<<4096, 256, 0, stream>>>(wi1, bi1, wh1, bh1, W1c, b1);
  k_embed<<<16384, 256, 0, stream>>>(tokens, casing, pos, emb, x_bf);
  k_init<<<1024, 256, 0, stream>>>(h_init, c_init, h0buf + (size_t)CH * SLOT,
                                   c_st);

  for (int t0 = 0; t0 < 256; t0 += CH) {
    for (int tl = 0; tl < CH; ++tl) {
      int t = t0 + tl;
      // input slot: tl-1; first step reads prev chunk's last slot (CH-1),
      // intact until its tl==CH-1 rewrite -- or h_init slot CH at t=0.
      int in_s = (tl > 0) ? (tl - 1) : ((t0 == 0) ? CH : CH - 1);
      k_step<<<1024, 256, 0, stream>>>(
          x_bf + (size_t)t * 81920, W0c, b0,
          h0buf + (size_t)in_s * SLOT,
          h0buf + (size_t)tl * SLOT,
          c0buf + (size_t)tl * SLOT, c_st);
    }
    k_l1gemm<<<64 * CH, 256, 0, stream>>>(h0buf, W1c, b1, c0buf, h1buf);
    k_decode<<<CH * 64, 256, 0, stream>>>(h0buf, h1buf, dec_w, dec_b, out, t0);
  }
}